// Round 1
// baseline (1063.254 us; speedup 1.0000x reference)
//
#include <hip/hip_runtime.h>
#include <hip/hip_cooperative_groups.h>

namespace cg = cooperative_groups;

#define NSRC 1024
#define MTGT 16384
#define DDIM 768
#define MAXIT 100

typedef __attribute__((ext_vector_type(8))) short bf16x8;
typedef __attribute__((ext_vector_type(4))) float f32x4;
typedef __attribute__((ext_vector_type(4))) unsigned short u16x4;

__device__ __forceinline__ unsigned short f2bf(float f) {
  unsigned u = __float_as_uint(f);
  u += 0x7FFFu + ((u >> 16) & 1u);
  return (unsigned short)(u >> 16);
}

// ---------------- kernel 1: row squared-norms ----------------
// grid: NSRC + MTGT blocks of 192 threads (one row each, float4/thread)
__global__ void ot_norms_kernel(const float* __restrict__ src, const float* __restrict__ tgt,
                                float* __restrict__ ssq, float* __restrict__ tsq) {
  __shared__ float sbuf[3];
  int row = blockIdx.x;
  const float* base = (row < NSRC) ? (src + (size_t)row * DDIM)
                                   : (tgt + (size_t)(row - NSRC) * DDIM);
  float4 v = *(const float4*)(base + threadIdx.x * 4);
  float acc = v.x * v.x + v.y * v.y + v.z * v.z + v.w * v.w;
  #pragma unroll
  for (int off = 32; off > 0; off >>= 1) acc += __shfl_down(acc, off, 64);
  int wave = threadIdx.x >> 6, lane = threadIdx.x & 63;
  if (lane == 0) sbuf[wave] = acc;
  __syncthreads();
  if (threadIdx.x == 0) {
    float t = sbuf[0] + sbuf[1] + sbuf[2];
    if (row < NSRC) ssq[row] = t; else tsq[row - NSRC] = t;
  }
}

// ---------------- kernel 2: K = exp(-cost/eps) via bf16 MFMA GEMM ----------------
// 128x128 tile, BK=32, 256 threads (4 waves, 2x2), each wave 64x64 = 4x4 frags of 16x16x32.
__global__ __launch_bounds__(256) void ot_gemmk_kernel(
    const float* __restrict__ src, const float* __restrict__ tgt,
    const float* __restrict__ ssq, const float* __restrict__ tsq,
    float* __restrict__ Kmat) {
  __shared__ __align__(16) short As[128 * 32];
  __shared__ __align__(16) short Bs[128 * 32];
  const int bm = blockIdx.x & 7, bn = blockIdx.x >> 3;
  const int row0 = bm * 128, col0 = bn * 128;
  const int tid = threadIdx.x;
  const int lane = tid & 63, wave = tid >> 6;
  const int wm = wave >> 1, wn = wave & 1;
  const int lr = lane & 15, hi = lane >> 4;

  f32x4 acc[4][4];
  #pragma unroll
  for (int mi = 0; mi < 4; ++mi)
    #pragma unroll
    for (int ni = 0; ni < 4; ++ni) acc[mi][ni] = (f32x4){0.f, 0.f, 0.f, 0.f};

  for (int kt = 0; kt < DDIM / 32; ++kt) {
    __syncthreads();
    // stage: fp32 -> bf16 into LDS. 1024 float4 chunks per tile, 4 per thread.
    #pragma unroll
    for (int q = 0; q < 4; ++q) {
      int chunk = tid + q * 256;            // 0..1023
      int r = chunk >> 3, c4 = chunk & 7;   // row in tile, float4 within row
      float4 av = *(const float4*)(src + (size_t)(row0 + r) * DDIM + kt * 32 + c4 * 4);
      u16x4 ab; ab[0] = f2bf(av.x); ab[1] = f2bf(av.y); ab[2] = f2bf(av.z); ab[3] = f2bf(av.w);
      *(u16x4*)(&As[r * 32 + c4 * 4]) = ab;
      float4 bv = *(const float4*)(tgt + (size_t)(col0 + r) * DDIM + kt * 32 + c4 * 4);
      u16x4 bb; bb[0] = f2bf(bv.x); bb[1] = f2bf(bv.y); bb[2] = f2bf(bv.z); bb[3] = f2bf(bv.w);
      *(u16x4*)(&Bs[r * 32 + c4 * 4]) = bb;
    }
    __syncthreads();
    bf16x8 a[4], b[4];
    #pragma unroll
    for (int mi = 0; mi < 4; ++mi)
      a[mi] = *(const bf16x8*)(&As[(wm * 64 + mi * 16 + lr) * 32 + hi * 8]);
    #pragma unroll
    for (int ni = 0; ni < 4; ++ni)
      b[ni] = *(const bf16x8*)(&Bs[(wn * 64 + ni * 16 + lr) * 32 + hi * 8]);
    #pragma unroll
    for (int mi = 0; mi < 4; ++mi)
      #pragma unroll
      for (int ni = 0; ni < 4; ++ni)
        acc[mi][ni] = __builtin_amdgcn_mfma_f32_16x16x32_bf16(a[mi], b[ni], acc[mi][ni], 0, 0, 0);
  }

  // epilogue: K = exp2(-(log2e/eps) * cost)
  const float SC = 14.426950408889634f;  // log2(e)/0.1
  #pragma unroll
  for (int mi = 0; mi < 4; ++mi) {
    #pragma unroll
    for (int ni = 0; ni < 4; ++ni) {
      int col = col0 + wn * 64 + ni * 16 + lr;
      float tq = tsq[col];
      #pragma unroll
      for (int e = 0; e < 4; ++e) {
        int row = row0 + wm * 64 + mi * 16 + hi * 4 + e;
        float cost = ssq[row] + tq - 2.0f * acc[mi][ni][e];
        Kmat[(size_t)row * MTGT + col] = exp2f(-SC * cost);
      }
    }
  }
}

// ---------------- kernel 3: cooperative Sinkhorn + final OT reduction ----------------
__device__ __forceinline__ float blockReduceSum4(float val, float* sbuf) {
  #pragma unroll
  for (int off = 32; off > 0; off >>= 1) val += __shfl_down(val, off, 64);
  int lane = threadIdx.x & 63, wave = threadIdx.x >> 6;
  if (lane == 0) sbuf[wave] = val;
  __syncthreads();
  float r = 0.f;
  if (threadIdx.x < 4) r = sbuf[threadIdx.x];
  r += __shfl_down(r, 2, 64);
  r += __shfl_down(r, 1, 64);
  __syncthreads();
  return r;  // valid on tid 0
}

__global__ __launch_bounds__(256) void ot_sinkhorn_kernel(
    const float* __restrict__ Kmat, float* __restrict__ u, float* __restrict__ unew,
    float* __restrict__ v, float* __restrict__ KTu, unsigned* __restrict__ errb,
    float* __restrict__ ot, float* __restrict__ out) {
  cg::grid_group grid = cg::this_grid();
  __shared__ float sbuf[4];
  const int tid = threadIdx.x;
  const int bid = blockIdx.x;
  const int gid = bid * 256 + tid;
  const float A_VAL = 1.0f / NSRC;
  const float B_VAL = 1.0f / MTGT;

  // init (ws is poisoned 0xAA before every launch)
  if (gid < MTGT) v[gid] = 1.0f;
  if (gid < NSRC) u[gid] = 1.0f;
  if (gid < MAXIT) errb[gid] = 0u;
  if (gid == 0) *ot = 0.0f;
  grid.sync();

  for (int it = 0; it < MAXIT; ++it) {
    // phase 1: Kv (row bid), u_new = a/(Kv+1e-10), err; zero KTu
    {
      const float4* Kr = (const float4*)(Kmat + (size_t)bid * MTGT);
      const float4* v4 = (const float4*)v;
      float acc = 0.f;
      #pragma unroll 4
      for (int q = 0; q < 16; ++q) {
        int idx = tid + q * 256;
        float4 k4 = Kr[idx]; float4 vv = v4[idx];
        acc += k4.x * vv.x + k4.y * vv.y + k4.z * vv.z + k4.w * vv.w;
      }
      float tot = blockReduceSum4(acc, sbuf);
      if (tid == 0) {
        float un = A_VAL / (tot + 1e-10f);
        unew[bid] = un;
        float d = fabsf(un - u[bid]);
        atomicMax(&errb[it], __float_as_uint(d));  // d >= 0: bits are order-preserving
      }
      if (tid < 16) KTu[bid * 16 + tid] = 0.0f;
    }
    grid.sync();
    // phase 2: KTu += K^T u_new (16 colchunks x 64 rowchunks of 16 rows)
    {
      int cc = (bid & 15) * 1024 + tid * 4;
      int i0 = (bid >> 4) * 16;
      float4 a4 = {0.f, 0.f, 0.f, 0.f};
      #pragma unroll 4
      for (int i = i0; i < i0 + 16; ++i) {
        float ui = unew[i];
        float4 k4 = *(const float4*)(Kmat + (size_t)i * MTGT + cc);
        a4.x += k4.x * ui; a4.y += k4.y * ui; a4.z += k4.z * ui; a4.w += k4.w * ui;
      }
      atomicAdd(&KTu[cc + 0], a4.x); atomicAdd(&KTu[cc + 1], a4.y);
      atomicAdd(&KTu[cc + 2], a4.z); atomicAdd(&KTu[cc + 3], a4.w);
    }
    grid.sync();
    // phase 3: v = b/(KTu+1e-10); u <- u_new; convergence check
    bool done;
    {
      if (gid < MTGT) v[gid] = B_VAL / (KTu[gid] + 1e-10f);
      else if (gid - MTGT < NSRC) u[gid - MTGT] = unew[gid - MTGT];
      done = (__uint_as_float(errb[it]) < 0.001f);
    }
    grid.sync();
    if (done) break;  // post-update freeze == reference's done-latch semantics
  }

  // final: ot = sum u_i K_ij v_j * (-eps*ln(K_ij)); loss = sqrt(ot/(n+m)+1e-8)
  {
    const float4* K4 = (const float4*)Kmat;
    const float4* V4 = (const float4*)v;
    float acc = 0.f;
    #pragma unroll 4
    for (int idx = gid; idx < (NSRC * MTGT / 4); idx += 256 * 1024) {
      float4 k4 = K4[idx];
      int i = idx >> 12;         // 4096 float4 per row
      float ui = u[i];
      float4 vv = V4[idx & 4095];
      acc += (k4.x > 0.f) ? ui * k4.x * vv.x * (-0.1f * __logf(k4.x)) : 0.f;
      acc += (k4.y > 0.f) ? ui * k4.y * vv.y * (-0.1f * __logf(k4.y)) : 0.f;
      acc += (k4.z > 0.f) ? ui * k4.z * vv.z * (-0.1f * __logf(k4.z)) : 0.f;
      acc += (k4.w > 0.f) ? ui * k4.w * vv.w * (-0.1f * __logf(k4.w)) : 0.f;
    }
    float tot = blockReduceSum4(acc, sbuf);
    if (tid == 0) atomicAdd(ot, tot);
  }
  grid.sync();
  if (gid == 0) out[0] = sqrtf(*ot / (float)(NSRC + MTGT) + 1e-8f);
}

// ---------------- launcher ----------------
extern "C" void kernel_launch(void* const* d_in, const int* in_sizes, int n_in,
                              void* d_out, int out_size, void* d_ws, size_t ws_size,
                              hipStream_t stream) {
  const float* src = (const float*)d_in[0];  // (16,64,768)  -> 1024 x 768
  const float* tgt = (const float*)d_in[1];  // (16,1024,768)-> 16384 x 768
  float* out = (float*)d_out;
  char* ws = (char*)d_ws;

  // workspace layout (bytes)
  float* Kmat = (float*)(ws + 0);                       // 64 MB
  float* ssq  = (float*)(ws + 67108864);                // 4 KB
  float* tsq  = (float*)(ws + 67112960);                // 64 KB
  float* u    = (float*)(ws + 67178496);                // 4 KB
  float* unew = (float*)(ws + 67182592);                // 4 KB
  float* v    = (float*)(ws + 67186688);                // 64 KB
  float* KTu  = (float*)(ws + 67252224);                // 64 KB
  unsigned* errb = (unsigned*)(ws + 67317760);          // 512 B
  float* ot   = (float*)(ws + 67318272);                // 4 B

  ot_norms_kernel<<<NSRC + MTGT, 192, 0, stream>>>(src, tgt, ssq, tsq);
  ot_gemmk_kernel<<<(NSRC / 128) * (MTGT / 128), 256, 0, stream>>>(src, tgt, ssq, tsq, Kmat);

  const float* Kc = Kmat;
  void* kargs[] = {(void*)&Kc, (void*)&u, (void*)&unew, (void*)&v,
                   (void*)&KTu, (void*)&errb, (void*)&ot, (void*)&out};
  hipLaunchCooperativeKernel((void*)ot_sinkhorn_kernel, dim3(NSRC), dim3(256),
                             kargs, 0, stream);
}

// Round 2
// 415.908 us; speedup vs baseline: 2.5565x; 2.5565x over previous
//
#include <hip/hip_runtime.h>

#define NSRC 1024
#define MTGT 16384
#define DDIM 768
#define MAXIT 100
#define NBLK 256
#define NTHR 1024

typedef __attribute__((ext_vector_type(8))) short bf16x8;
typedef __attribute__((ext_vector_type(4))) float f32x4;
typedef __attribute__((ext_vector_type(4))) unsigned short u16x4;

__device__ __forceinline__ unsigned short f2bf(float f) {
  unsigned u = __float_as_uint(f);
  u += 0x7FFFu + ((u >> 16) & 1u);
  return (unsigned short)(u >> 16);
}

// ---------------- kernel 1: row squared-norms ----------------
__global__ void ot_norms_kernel(const float* __restrict__ src, const float* __restrict__ tgt,
                                float* __restrict__ ssq, float* __restrict__ tsq) {
  __shared__ float sbuf[3];
  int row = blockIdx.x;
  const float* base = (row < NSRC) ? (src + (size_t)row * DDIM)
                                   : (tgt + (size_t)(row - NSRC) * DDIM);
  float4 v = *(const float4*)(base + threadIdx.x * 4);
  float acc = v.x * v.x + v.y * v.y + v.z * v.z + v.w * v.w;
  #pragma unroll
  for (int off = 32; off > 0; off >>= 1) acc += __shfl_down(acc, off, 64);
  int wave = threadIdx.x >> 6, lane = threadIdx.x & 63;
  if (lane == 0) sbuf[wave] = acc;
  __syncthreads();
  if (threadIdx.x == 0) {
    float t = sbuf[0] + sbuf[1] + sbuf[2];
    if (row < NSRC) ssq[row] = t; else tsq[row - NSRC] = t;
  }
}

// ---------------- kernel 2: K = exp(-cost/eps) via bf16 MFMA GEMM ----------------
__global__ __launch_bounds__(256) void ot_gemmk_kernel(
    const float* __restrict__ src, const float* __restrict__ tgt,
    const float* __restrict__ ssq, const float* __restrict__ tsq,
    float* __restrict__ Kmat) {
  __shared__ __align__(16) short As[128 * 32];
  __shared__ __align__(16) short Bs[128 * 32];
  const int bm = blockIdx.x & 7, bn = blockIdx.x >> 3;
  const int row0 = bm * 128, col0 = bn * 128;
  const int tid = threadIdx.x;
  const int lane = tid & 63, wave = tid >> 6;
  const int wm = wave >> 1, wn = wave & 1;
  const int lr = lane & 15, hi = lane >> 4;

  f32x4 acc[4][4];
  #pragma unroll
  for (int mi = 0; mi < 4; ++mi)
    #pragma unroll
    for (int ni = 0; ni < 4; ++ni) acc[mi][ni] = (f32x4){0.f, 0.f, 0.f, 0.f};

  for (int kt = 0; kt < DDIM / 32; ++kt) {
    __syncthreads();
    #pragma unroll
    for (int q = 0; q < 4; ++q) {
      int chunk = tid + q * 256;
      int r = chunk >> 3, c4 = chunk & 7;
      float4 av = *(const float4*)(src + (size_t)(row0 + r) * DDIM + kt * 32 + c4 * 4);
      u16x4 ab; ab[0] = f2bf(av.x); ab[1] = f2bf(av.y); ab[2] = f2bf(av.z); ab[3] = f2bf(av.w);
      *(u16x4*)(&As[r * 32 + c4 * 4]) = ab;
      float4 bv = *(const float4*)(tgt + (size_t)(col0 + r) * DDIM + kt * 32 + c4 * 4);
      u16x4 bb; bb[0] = f2bf(bv.x); bb[1] = f2bf(bv.y); bb[2] = f2bf(bv.z); bb[3] = f2bf(bv.w);
      *(u16x4*)(&Bs[r * 32 + c4 * 4]) = bb;
    }
    __syncthreads();
    bf16x8 a[4], b[4];
    #pragma unroll
    for (int mi = 0; mi < 4; ++mi)
      a[mi] = *(const bf16x8*)(&As[(wm * 64 + mi * 16 + lr) * 32 + hi * 8]);
    #pragma unroll
    for (int ni = 0; ni < 4; ++ni)
      b[ni] = *(const bf16x8*)(&Bs[(wn * 64 + ni * 16 + lr) * 32 + hi * 8]);
    #pragma unroll
    for (int mi = 0; mi < 4; ++mi)
      #pragma unroll
      for (int ni = 0; ni < 4; ++ni)
        acc[mi][ni] = __builtin_amdgcn_mfma_f32_16x16x32_bf16(a[mi], b[ni], acc[mi][ni], 0, 0, 0);
  }

  const float SC = 14.426950408889634f;  // log2(e)/0.1
  #pragma unroll
  for (int mi = 0; mi < 4; ++mi) {
    #pragma unroll
    for (int ni = 0; ni < 4; ++ni) {
      int col = col0 + wn * 64 + ni * 16 + lr;
      float tq = tsq[col];
      #pragma unroll
      for (int e = 0; e < 4; ++e) {
        int row = row0 + wm * 64 + mi * 16 + hi * 4 + e;
        float cost = ssq[row] + tq - 2.0f * acc[mi][ni][e];
        Kmat[(size_t)row * MTGT + col] = exp2f(-SC * cost);
      }
    }
  }
}

// ---------------- custom grid barrier (replaces cg::grid.sync) ----------------
__device__ __forceinline__ void grid_barrier(unsigned* arrive, unsigned* gen, unsigned& myGen) {
  __syncthreads();
  if (threadIdx.x == 0) {
    unsigned target = myGen + 1;
    __threadfence();
    unsigned old = __hip_atomic_fetch_add(arrive, 1u, __ATOMIC_ACQ_REL, __HIP_MEMORY_SCOPE_AGENT);
    if (old == (unsigned)(NBLK - 1)) {
      __hip_atomic_store(arrive, 0u, __ATOMIC_RELAXED, __HIP_MEMORY_SCOPE_AGENT);
      __hip_atomic_store(gen, target, __ATOMIC_RELEASE, __HIP_MEMORY_SCOPE_AGENT);
    } else {
      while (__hip_atomic_load(gen, __ATOMIC_ACQUIRE, __HIP_MEMORY_SCOPE_AGENT) < target)
        __builtin_amdgcn_s_sleep(2);
    }
    myGen = target;
    __threadfence();
  }
  __syncthreads();
}

// ---------------- kernel 3: Sinkhorn + final OT reduction ----------------
// 256 blocks x 1024 threads. Phase A: block owns 4 rows (u update).
// Phase B: block owns 64 cols (K^T u -> v update, NO atomics). 2 barriers/iter.
__global__ __launch_bounds__(NTHR) void ot_sinkhorn_kernel(
    const float* __restrict__ Kmat, float* __restrict__ u, float* __restrict__ unew,
    float* __restrict__ v, unsigned* __restrict__ errb,
    float* __restrict__ ot, float* __restrict__ out,
    unsigned* arrive, unsigned* gen) {
  __shared__ float sbuf[NTHR];
  const int tid = threadIdx.x, bid = blockIdx.x;
  const int gid = bid * NTHR + tid;
  unsigned myGen = 0;
  const float A_VAL = 1.0f / NSRC, B_VAL = 1.0f / MTGT;

  // block 0 inits control state, publishes gen=0 (ws arrives poisoned 0xAA)
  if (bid == 0) {
    for (int i = tid; i < MAXIT; i += NTHR) errb[i] = 0u;
    if (tid == 0) {
      *ot = 0.0f;
      __hip_atomic_store(arrive, 0u, __ATOMIC_RELAXED, __HIP_MEMORY_SCOPE_AGENT);
    }
    __syncthreads();
    if (tid == 0) __hip_atomic_store(gen, 0u, __ATOMIC_RELEASE, __HIP_MEMORY_SCOPE_AGENT);
  }
  // everyone: init u, v
  if (gid < MTGT) v[gid] = 1.0f;
  else if (gid - MTGT < NSRC) u[gid - MTGT] = 1.0f;
  // handshake: wait for control state ready
  if (tid == 0)
    while (__hip_atomic_load(gen, __ATOMIC_ACQUIRE, __HIP_MEMORY_SCOPE_AGENT) != 0u)
      __builtin_amdgcn_s_sleep(2);
  grid_barrier(arrive, gen, myGen);  // #1: all init visible

  for (int it = 0; it < MAXIT; ++it) {
    // ---- phase A: unew_i = a / (K v)_i, err ----
    {
      const int r = tid >> 8, lane = tid & 255;
      const int row = (bid << 2) + r;
      const float4* Kr = (const float4*)(Kmat + (size_t)row * MTGT);
      const float4* v4 = (const float4*)v;
      float acc = 0.f;
      #pragma unroll
      for (int q = 0; q < 16; ++q) {
        int idx = lane + q * 256;
        float4 k4 = Kr[idx], vv = v4[idx];
        acc += k4.x * vv.x + k4.y * vv.y + k4.z * vv.z + k4.w * vv.w;
      }
      #pragma unroll
      for (int off = 32; off > 0; off >>= 1) acc += __shfl_down(acc, off, 64);
      if ((tid & 63) == 0) sbuf[tid >> 6] = acc;
      __syncthreads();
      if ((tid & 255) == 0) {
        float tot = sbuf[(r << 2)] + sbuf[(r << 2) | 1] + sbuf[(r << 2) | 2] + sbuf[(r << 2) | 3];
        float un = A_VAL / (tot + 1e-10f);
        unew[row] = un;
        atomicMax(&errb[it], __float_as_uint(fabsf(un - u[row])));
      }
    }
    grid_barrier(arrive, gen, myGen);  // unew, errb visible
    // ---- phase B: v_j = b / (K^T unew)_j (column-owned), u <- unew ----
    {
      const int cl = tid & 63, rg = tid >> 6;
      const int col = (bid << 6) + cl;
      float acc = 0.f;
      #pragma unroll 8
      for (int i = rg; i < NSRC; i += 16)
        acc += Kmat[(size_t)i * MTGT + col] * unew[i];
      sbuf[tid] = acc;
      __syncthreads();
      if (tid < 64) {
        float t = 0.f;
        #pragma unroll
        for (int k = 0; k < 16; ++k) t += sbuf[tid + (k << 6)];
        v[(bid << 6) + tid] = B_VAL / (t + 1e-10f);
      } else if (tid < 68) {
        int i = (bid << 2) + (tid - 64);
        u[i] = unew[i];
      }
    }
    bool done = (__uint_as_float(errb[it]) < 0.001f);
    grid_barrier(arrive, gen, myGen);  // v, u visible
    if (done) break;  // uniform across grid (errb read post-barrier-A)
  }

  // ---- final: ot = sum u_i K_ij v_j * (-eps ln K_ij) ----
  {
    const float4* K4 = (const float4*)Kmat;
    const float4* V4 = (const float4*)v;
    float acc = 0.f;
    for (int idx = gid; idx < (NSRC * MTGT / 4); idx += NBLK * NTHR) {
      float4 k4 = K4[idx];
      float ui = u[idx >> 12];
      float4 vv = V4[idx & 4095];
      acc += (k4.x > 0.f) ? ui * k4.x * vv.x * (-0.1f * __logf(k4.x)) : 0.f;
      acc += (k4.y > 0.f) ? ui * k4.y * vv.y * (-0.1f * __logf(k4.y)) : 0.f;
      acc += (k4.z > 0.f) ? ui * k4.z * vv.z * (-0.1f * __logf(k4.z)) : 0.f;
      acc += (k4.w > 0.f) ? ui * k4.w * vv.w * (-0.1f * __logf(k4.w)) : 0.f;
    }
    #pragma unroll
    for (int off = 32; off > 0; off >>= 1) acc += __shfl_down(acc, off, 64);
    if ((tid & 63) == 0) sbuf[tid >> 6] = acc;
    __syncthreads();
    if (tid == 0) {
      float tot = 0.f;
      #pragma unroll
      for (int k = 0; k < 16; ++k) tot += sbuf[k];
      atomicAdd(ot, tot);
    }
  }
  grid_barrier(arrive, gen, myGen);
  if (gid == 0) out[0] = sqrtf(*ot / (float)(NSRC + MTGT) + 1e-8f);
}

// ---------------- launcher ----------------
extern "C" void kernel_launch(void* const* d_in, const int* in_sizes, int n_in,
                              void* d_out, int out_size, void* d_ws, size_t ws_size,
                              hipStream_t stream) {
  const float* src = (const float*)d_in[0];  // 1024 x 768
  const float* tgt = (const float*)d_in[1];  // 16384 x 768
  float* out = (float*)d_out;
  char* ws = (char*)d_ws;

  float* Kmat = (float*)(ws + 0);               // 64 MB
  float* ssq  = (float*)(ws + 67108864);        // 4 KB
  float* tsq  = (float*)(ws + 67112960);        // 64 KB
  float* u    = (float*)(ws + 67178496);        // 4 KB
  float* unew = (float*)(ws + 67182592);        // 4 KB
  float* v    = (float*)(ws + 67186688);        // 64 KB
  unsigned* errb = (unsigned*)(ws + 67252224);  // 400 B
  float* ot   = (float*)(ws + 67256320);        // 4 B
  unsigned* arrive = (unsigned*)(ws + 67256448);
  unsigned* gen    = (unsigned*)(ws + 67256704);

  ot_norms_kernel<<<NSRC + MTGT, 192, 0, stream>>>(src, tgt, ssq, tsq);
  ot_gemmk_kernel<<<(NSRC / 128) * (MTGT / 128), 256, 0, stream>>>(src, tgt, ssq, tsq, Kmat);

  const float* Kc = Kmat;
  void* kargs[] = {(void*)&Kc, (void*)&u, (void*)&unew, (void*)&v,
                   (void*)&errb, (void*)&ot, (void*)&out, (void*)&arrive, (void*)&gen};
  hipLaunchCooperativeKernel((void*)ot_sinkhorn_kernel, dim3(NBLK), dim3(NTHR),
                             kargs, 0, stream);
}

// Round 4
// 279.851 us; speedup vs baseline: 3.7994x; 1.4862x over previous
//
#include <hip/hip_runtime.h>

#define NSRC 1024
#define MTGT 16384
#define DDIM 768
#define MAXIT 100
#define NBLK 256
#define NTHR 1024
#define NGRP 16
#define GRPSZ 16

typedef __attribute__((ext_vector_type(8))) short bf16x8;
typedef __attribute__((ext_vector_type(4))) float f32x4;
typedef __attribute__((ext_vector_type(4))) unsigned short u16x4;
typedef __attribute__((ext_vector_type(8))) unsigned short u16x8;

__device__ __forceinline__ unsigned short f2bf(float f) {
  unsigned u = __float_as_uint(f);
  u += 0x7FFFu + ((u >> 16) & 1u);
  return (unsigned short)(u >> 16);
}
__device__ __forceinline__ float bf2f(unsigned short h) {
  return __uint_as_float(((unsigned)h) << 16);
}
// agent-scope relaxed (coherence-point) accessors: no stale copies, no fences
__device__ __forceinline__ void gstoref(float* p, float x) {
  __hip_atomic_store(p, x, __ATOMIC_RELAXED, __HIP_MEMORY_SCOPE_AGENT);
}
__device__ __forceinline__ float gloadf(const float* p) {
  return __hip_atomic_load(p, __ATOMIC_RELAXED, __HIP_MEMORY_SCOPE_AGENT);
}
__device__ __forceinline__ unsigned gloadu(const unsigned* p) {
  return __hip_atomic_load(p, __ATOMIC_RELAXED, __HIP_MEMORY_SCOPE_AGENT);
}

// ---------------- kernel 1: row squared-norms ----------------
__global__ void ot_norms_kernel(const float* __restrict__ src, const float* __restrict__ tgt,
                                float* __restrict__ ssq, float* __restrict__ tsq) {
  __shared__ float sbuf[3];
  int row = blockIdx.x;
  const float* base = (row < NSRC) ? (src + (size_t)row * DDIM)
                                   : (tgt + (size_t)(row - NSRC) * DDIM);
  float4 v = *(const float4*)(base + threadIdx.x * 4);
  float acc = v.x * v.x + v.y * v.y + v.z * v.z + v.w * v.w;
  #pragma unroll
  for (int off = 32; off > 0; off >>= 1) acc += __shfl_down(acc, off, 64);
  int wave = threadIdx.x >> 6, lane = threadIdx.x & 63;
  if (lane == 0) sbuf[wave] = acc;
  __syncthreads();
  if (threadIdx.x == 0) {
    float t = sbuf[0] + sbuf[1] + sbuf[2];
    if (row < NSRC) ssq[row] = t; else tsq[row - NSRC] = t;
  }
}

// ---------------- kernel 2: Kb(bf16) = exp(-cost/eps), fused row-sums ----------------
__global__ __launch_bounds__(256) void ot_gemmk_kernel(
    const float* __restrict__ src, const float* __restrict__ tgt,
    const float* __restrict__ ssq, const float* __restrict__ tsq,
    unsigned short* __restrict__ Kb, float* __restrict__ rowsum) {
  __shared__ __align__(16) short As[128 * 32];
  __shared__ __align__(16) short Bs[128 * 32];
  // XCD-bijective swizzle: 1024 blocks, 8 XCDs -> each XCD owns 16 bn columns
  const int wgid = (blockIdx.x & 7) * 128 + (blockIdx.x >> 3);
  const int bm = wgid & 7, bn = wgid >> 3;
  const int row0 = bm * 128, col0 = bn * 128;
  const int tid = threadIdx.x;
  const int lane = tid & 63, wave = tid >> 6;
  const int wm = wave >> 1, wn = wave & 1;
  const int lr = lane & 15, hi = lane >> 4;

  f32x4 acc[4][4];
  #pragma unroll
  for (int mi = 0; mi < 4; ++mi)
    #pragma unroll
    for (int ni = 0; ni < 4; ++ni) acc[mi][ni] = (f32x4){0.f, 0.f, 0.f, 0.f};

  for (int kt = 0; kt < DDIM / 32; ++kt) {
    __syncthreads();
    #pragma unroll
    for (int q = 0; q < 4; ++q) {
      int chunk = tid + q * 256;
      int r = chunk >> 3, c4 = chunk & 7;
      float4 av = *(const float4*)(src + (size_t)(row0 + r) * DDIM + kt * 32 + c4 * 4);
      u16x4 ab; ab[0] = f2bf(av.x); ab[1] = f2bf(av.y); ab[2] = f2bf(av.z); ab[3] = f2bf(av.w);
      *(u16x4*)(&As[r * 32 + c4 * 4]) = ab;
      float4 bv = *(const float4*)(tgt + (size_t)(col0 + r) * DDIM + kt * 32 + c4 * 4);
      u16x4 bb; bb[0] = f2bf(bv.x); bb[1] = f2bf(bv.y); bb[2] = f2bf(bv.z); bb[3] = f2bf(bv.w);
      *(u16x4*)(&Bs[r * 32 + c4 * 4]) = bb;
    }
    __syncthreads();
    bf16x8 a[4], b[4];
    #pragma unroll
    for (int mi = 0; mi < 4; ++mi)
      a[mi] = *(const bf16x8*)(&As[(wm * 64 + mi * 16 + lr) * 32 + hi * 8]);
    #pragma unroll
    for (int ni = 0; ni < 4; ++ni)
      b[ni] = *(const bf16x8*)(&Bs[(wn * 64 + ni * 16 + lr) * 32 + hi * 8]);
    #pragma unroll
    for (int mi = 0; mi < 4; ++mi)
      #pragma unroll
      for (int ni = 0; ni < 4; ++ni)
        acc[mi][ni] = __builtin_amdgcn_mfma_f32_16x16x32_bf16(a[mi], b[ni], acc[mi][ni], 0, 0, 0);
  }

  const float SC = 14.426950408889634f;  // log2(e)/0.1
  int cols[4]; float tq[4];
  #pragma unroll
  for (int ni = 0; ni < 4; ++ni) { cols[ni] = col0 + wn * 64 + ni * 16 + lr; tq[ni] = tsq[cols[ni]]; }
  #pragma unroll
  for (int mi = 0; mi < 4; ++mi) {
    #pragma unroll
    for (int e = 0; e < 4; ++e) {
      int row = row0 + wm * 64 + mi * 16 + hi * 4 + e;
      float sq = ssq[row];
      float p = 0.f;
      #pragma unroll
      for (int ni = 0; ni < 4; ++ni) {
        float cost = sq + tq[ni] - 2.0f * acc[mi][ni][e];
        float k = exp2f(-SC * cost);
        Kb[(size_t)row * MTGT + cols[ni]] = f2bf(k);
        p += k;
      }
      p += __shfl_xor(p, 1, 64);
      p += __shfl_xor(p, 2, 64);
      p += __shfl_xor(p, 4, 64);
      p += __shfl_xor(p, 8, 64);  // sum across the 16 lanes sharing `hi`
      if (lr == 0) atomicAdd(&rowsum[row], p);
    }
  }
}

// ---------------- fence-free two-level tree barrier ----------------
// monotonic counters (no resets); all cross-block data exchange is via
// coherence-point atomics, so no acquire/release cache maintenance needed.
__device__ __forceinline__ void grid_barrier(unsigned* garr, unsigned* root,
                                             unsigned* gen, unsigned& t) {
  __syncthreads();
  if (threadIdx.x == 0) {
    asm volatile("s_waitcnt vmcnt(0)" ::: "memory");
    unsigned g = (unsigned)(blockIdx.x >> 4);  // 16 groups of 16
    unsigned old = __hip_atomic_fetch_add(&garr[g * 64], 1u, __ATOMIC_RELAXED,
                                          __HIP_MEMORY_SCOPE_AGENT);
    if (old == t * GRPSZ + (GRPSZ - 1)) {
      unsigned r = __hip_atomic_fetch_add(root, 1u, __ATOMIC_RELAXED,
                                          __HIP_MEMORY_SCOPE_AGENT);
      if (r == t * NGRP + (NGRP - 1)) {
        __hip_atomic_store(gen, t + 1u, __ATOMIC_RELAXED, __HIP_MEMORY_SCOPE_AGENT);
      } else {
        while (gloadu(gen) < t + 1u) __builtin_amdgcn_s_sleep(1);
      }
    } else {
      while (gloadu(gen) < t + 1u) __builtin_amdgcn_s_sleep(1);
    }
    t += 1u;
  }
  __syncthreads();
}

// ---------------- kernel 3: Sinkhorn + fused final reduction ----------------
// phase0: u1 = a/(rowsum+1e-10)           [row-sums fused in GEMM]
// it loop: [A: unew = a/(K v + 1e-10)]  [B: v = b/(K^T unew + 1e-10); if last,
//          also accumulate ot = sum_ij unew_i K_ij v_j * (-eps ln K_ij)]
__global__ __launch_bounds__(NTHR) void ot_sinkhorn_kernel(
    const unsigned short* __restrict__ Kb, const float* __restrict__ rowsum,
    float* unew, float* v, unsigned* errb, float* ot, float* __restrict__ out,
    unsigned* garr, unsigned* root, unsigned* gen) {
  __shared__ float smem[16384];  // phase A: v staging (64 KB); phase B: aliased
  const int tid = threadIdx.x, bid = blockIdx.x;
  unsigned bt = 0;  // barrier generation
  const float A_VAL = 1.0f / NSRC, B_VAL = 1.0f / MTGT;
  float uprev = 0.f;  // live in row-owner threads (tid % 256 == 0)

  // ---- phase 0: closed-form it0 phase A from GEMM row-sums ----
  if ((tid & 255) == 0) {
    int row = (bid << 2) + (tid >> 8);
    float un = A_VAL / (rowsum[row] + 1e-10f);
    uprev = un;
    gstoref(&unew[row], un);
    atomicMax(&errb[0], __float_as_uint(fabsf(un - 1.0f)));
  }
  grid_barrier(garr, root, gen, bt);

  for (int it = 0; it < MAXIT; ++it) {
    if (it > 0) {
      // ---- phase A: unew_i = a / (K v)_i ----
      #pragma unroll
      for (int q = 0; q < 16; ++q) {
        int j = tid + q * 1024;
        smem[j] = gloadf(&v[j]);
      }
      __syncthreads();
      const int r = tid >> 8, l2 = tid & 255;
      const int row = (bid << 2) + r;
      const u16x8* Kr = (const u16x8*)(Kb + (size_t)row * MTGT);
      float acc = 0.f;
      #pragma unroll
      for (int q = 0; q < 8; ++q) {
        int c8 = l2 + q * 256;
        u16x8 k8 = Kr[c8];
        float4 v0 = *(const float4*)(&smem[c8 * 8]);
        float4 v1 = *(const float4*)(&smem[c8 * 8 + 4]);
        acc += bf2f(k8[0]) * v0.x + bf2f(k8[1]) * v0.y +
               bf2f(k8[2]) * v0.z + bf2f(k8[3]) * v0.w +
               bf2f(k8[4]) * v1.x + bf2f(k8[5]) * v1.y +
               bf2f(k8[6]) * v1.z + bf2f(k8[7]) * v1.w;
      }
      __syncthreads();  // all smem reads done; reuse smem[0..15]
      #pragma unroll
      for (int off = 32; off > 0; off >>= 1) acc += __shfl_down(acc, off, 64);
      if ((tid & 63) == 0) smem[tid >> 6] = acc;
      __syncthreads();
      if ((tid & 255) == 0) {
        float tot = smem[r * 4] + smem[r * 4 + 1] + smem[r * 4 + 2] + smem[r * 4 + 3];
        float un = A_VAL / (tot + 1e-10f);
        atomicMax(&errb[it], __float_as_uint(fabsf(un - uprev)));
        uprev = un;
        gstoref(&unew[row], un);
      }
      grid_barrier(garr, root, gen, bt);
    }
    // ---- phase B: v_j = b / (K^T unew)_j ; fused final on last iteration ----
    bool done = (__uint_as_float(gloadu(&errb[it])) < 0.001f);
    bool last = done || (it == MAXIT - 1);
    float* ulds = smem + 2048;     // [1024]
    float* tbuf = smem;            // [1024]
    float* wbuf = smem + 1024;     // [1024]
    ulds[tid] = gloadf(&unew[tid]);  // NTHR == NSRC
    __syncthreads();
    {
      const int cl = tid & 63, rg = tid >> 6;
      const int col = (bid << 6) + cl;
      float t = 0.f, w = 0.f;
      #pragma unroll 8
      for (int i = rg; i < NSRC; i += 16) {
        float ui = ulds[i];
        float k = bf2f(Kb[(size_t)i * MTGT + col]);
        t += k * ui;
        if (last) w += (k > 0.f) ? ui * k * (-0.1f * __logf(k)) : 0.f;
      }
      tbuf[tid] = t;
      if (last) wbuf[tid] = w;
    }
    __syncthreads();
    if (tid < 64) {
      float tt = 0.f, ww = 0.f;
      #pragma unroll
      for (int k16 = 0; k16 < 16; ++k16) {
        tt += tbuf[tid + k16 * 64];
        if (last) ww += wbuf[tid + k16 * 64];
      }
      float vj = B_VAL / (tt + 1e-10f);
      gstoref(&v[(bid << 6) + tid], vj);
      if (last) {
        float term = ww * vj;
        #pragma unroll
        for (int off = 32; off > 0; off >>= 1) term += __shfl_down(term, off, 64);
        if (tid == 0) atomicAdd(ot, term);
      }
    }
    grid_barrier(garr, root, gen, bt);
    if (done) break;
  }

  if (bid == 0 && tid == 0)
    out[0] = sqrtf(gloadf(ot) / (float)(NSRC + MTGT) + 1e-8f);
}

// ---------------- launcher ----------------
extern "C" void kernel_launch(void* const* d_in, const int* in_sizes, int n_in,
                              void* d_out, int out_size, void* d_ws, size_t ws_size,
                              hipStream_t stream) {
  const float* src = (const float*)d_in[0];  // 1024 x 768
  const float* tgt = (const float*)d_in[1];  // 16384 x 768
  float* out = (float*)d_out;
  char* ws = (char*)d_ws;

  unsigned short* Kb = (unsigned short*)ws;            // 32 MB bf16 K
  char* ctrl = ws + 33554432;                          // 16 KB, memset 0:
  float* rowsum = (float*)(ctrl);                      //   4 KB
  unsigned* errb = (unsigned*)(ctrl + 4096);           //   512 B
  float* ot = (float*)(ctrl + 4608);                   //   4 B (pad 256)
  unsigned* garr = (unsigned*)(ctrl + 4864);           //   16 x 256 B
  unsigned* root = (unsigned*)(ctrl + 8960);           //   256 B
  unsigned* gen  = (unsigned*)(ctrl + 9216);           //   256 B
  float* ssq  = (float*)(ws + 33571200);               // 4 KB
  float* tsq  = (float*)(ws + 33575296);               // 64 KB
  float* unew = (float*)(ws + 33640832);               // 4 KB
  float* v    = (float*)(ws + 33644928);               // 64 KB

  hipMemsetAsync(ctrl, 0, 16384, stream);
  ot_norms_kernel<<<NSRC + MTGT, 192, 0, stream>>>(src, tgt, ssq, tsq);
  ot_gemmk_kernel<<<(NSRC / 128) * (MTGT / 128), 256, 0, stream>>>(src, tgt, ssq, tsq, Kb, rowsum);

  const unsigned short* Kc = Kb;
  const float* rc = rowsum;
  void* kargs[] = {(void*)&Kc, (void*)&rc, (void*)&unew, (void*)&v,
                   (void*)&errb, (void*)&ot, (void*)&out,
                   (void*)&garr, (void*)&root, (void*)&gen};
  hipLaunchCooperativeKernel((void*)ot_sinkhorn_kernel, dim3(NBLK), dim3(NTHR),
                             kargs, 0, stream);
}

// Round 5
// 234.267 us; speedup vs baseline: 4.5386x; 1.1946x over previous
//
#include <hip/hip_runtime.h>

#define NSRC 1024
#define MTGT 16384
#define DDIM 768
#define MAXIT 100
#define NBLK 256
#define NTHR 1024
#define NGRP 16
#define GRPSZ 16

typedef __attribute__((ext_vector_type(8))) short bf16x8;
typedef __attribute__((ext_vector_type(4))) float f32x4;
typedef __attribute__((ext_vector_type(4))) unsigned short u16x4;
typedef __attribute__((ext_vector_type(8))) unsigned short u16x8;

__device__ __forceinline__ unsigned short f2bf(float f) {
  unsigned u = __float_as_uint(f);
  u += 0x7FFFu + ((u >> 16) & 1u);
  return (unsigned short)(u >> 16);
}
__device__ __forceinline__ float bf2f(unsigned short h) {
  return __uint_as_float(((unsigned)h) << 16);
}
// coherence-point (agent-scope relaxed) accessors for cross-block scalars
__device__ __forceinline__ void gstoref(float* p, float x) {
  __hip_atomic_store(p, x, __ATOMIC_RELAXED, __HIP_MEMORY_SCOPE_AGENT);
}
__device__ __forceinline__ float gloadf(const float* p) {
  return __hip_atomic_load(p, __ATOMIC_RELAXED, __HIP_MEMORY_SCOPE_AGENT);
}
__device__ __forceinline__ unsigned gloadu(const unsigned* p) {
  return __hip_atomic_load(p, __ATOMIC_RELAXED, __HIP_MEMORY_SCOPE_AGENT);
}
// async global->LDS, 16B per lane (dest must be linear: base + lane*16)
__device__ __forceinline__ void gl_lds16(const unsigned short* g, unsigned short* l) {
  __builtin_amdgcn_global_load_lds((__attribute__((address_space(1))) void*)g,
                                   (__attribute__((address_space(3))) void*)l, 16, 0, 0);
}

// ---------------- kernel 1: convert fp32->bf16 + row norms + zero ctrl ----------------
__global__ __launch_bounds__(192) void ot_convert_kernel(
    const float* __restrict__ src, const float* __restrict__ tgt,
    unsigned short* __restrict__ srcb, unsigned short* __restrict__ tgtb,
    float* __restrict__ ssq, float* __restrict__ tsq, unsigned* __restrict__ ctrl) {
  __shared__ float sbuf[3];
  const int row = blockIdx.x;
  const float* inp;
  unsigned short* outp;
  if (row < NSRC) { inp = src + (size_t)row * DDIM; outp = srcb + (size_t)row * DDIM; }
  else { inp = tgt + (size_t)(row - NSRC) * DDIM; outp = tgtb + (size_t)(row - NSRC) * DDIM; }
  float4 v = *(const float4*)(inp + threadIdx.x * 4);
  u16x4 b; b[0] = f2bf(v.x); b[1] = f2bf(v.y); b[2] = f2bf(v.z); b[3] = f2bf(v.w);
  *(u16x4*)(outp + threadIdx.x * 4) = b;
  float acc = v.x * v.x + v.y * v.y + v.z * v.z + v.w * v.w;
  #pragma unroll
  for (int off = 32; off > 0; off >>= 1) acc += __shfl_down(acc, off, 64);
  int wave = threadIdx.x >> 6, lane = threadIdx.x & 63;
  if (lane == 0) sbuf[wave] = acc;
  __syncthreads();
  if (threadIdx.x == 0) {
    float t = sbuf[0] + sbuf[1] + sbuf[2];
    if (row < NSRC) ssq[row] = t; else tsq[row - NSRC] = t;
  }
  if (row == 0) {  // zero control region (rowsum/errb/ot/barrier state)
    for (int i = threadIdx.x; i < 4096; i += 192) ctrl[i] = 0u;
  }
}

// ---------------- kernel 2: Kb(bf16) = exp(-cost/eps), m97-style staging ----------------
// 128x128 tile, BK=64, 4 waves (2x2), global_load_lds w/ source-swizzle.
__global__ __launch_bounds__(256) void ot_gemmk_kernel(
    const unsigned short* __restrict__ srcb, const unsigned short* __restrict__ tgtb,
    const float* __restrict__ ssq, const float* __restrict__ tsq,
    unsigned short* __restrict__ Kb, float* __restrict__ rowsum) {
  __shared__ __align__(16) unsigned short As[128 * 64];
  __shared__ __align__(16) unsigned short Bs[128 * 64];
  // XCD-grouped tiles: each XCD owns 16 contiguous tn columns (B-panel L2 reuse)
  const int tile = (blockIdx.x & 7) * 128 + (blockIdx.x >> 3);
  const int tm = tile & 7, tn = tile >> 3;
  const int row0 = tm * 128, col0 = tn * 128;
  const int tid = threadIdx.x, lane = tid & 63, wave = tid >> 6;
  const int wm = wave >> 1, wn = wave & 1;
  const int lr = lane & 15, hi = lane >> 4;

  f32x4 acc[4][4];
  #pragma unroll
  for (int fi = 0; fi < 4; ++fi)
    #pragma unroll
    for (int fj = 0; fj < 4; ++fj) acc[fi][fj] = (f32x4){0.f, 0.f, 0.f, 0.f};

  for (int kt = 0; kt < DDIM / 64; ++kt) {
    __syncthreads();  // previous iter's ds_reads done
    // stage 32 KB: 2048 chunks of 16B; chunk ch -> (r=ch>>3, c=ch&7); LDS linear,
    // global source pre-swizzled: logical k-chunk = c ^ (r&7)  [rule #21]
    #pragma unroll
    for (int q = 0; q < 4; ++q) {
      int ch = tid + q * 256;
      int r = ch >> 3, c = ch & 7;
      int cg = c ^ (r & 7);
      gl_lds16(srcb + (size_t)(row0 + r) * DDIM + kt * 64 + cg * 8, As + ch * 8);
      gl_lds16(tgtb + (size_t)(col0 + r) * DDIM + kt * 64 + cg * 8, Bs + ch * 8);
    }
    __syncthreads();  // barrier drains vmcnt -> LDS ready
    #pragma unroll
    for (int kc = 0; kc < 2; ++kc) {
      bf16x8 a[4], b[4];
      #pragma unroll
      for (int f = 0; f < 4; ++f) {
        int ra = wm * 64 + f * 16 + lr;
        a[f] = *(const bf16x8*)(As + ra * 64 + ((((kc << 2) | hi) ^ (ra & 7)) << 3));
        int rb = wn * 64 + f * 16 + lr;
        b[f] = *(const bf16x8*)(Bs + rb * 64 + ((((kc << 2) | hi) ^ (rb & 7)) << 3));
      }
      #pragma unroll
      for (int fi = 0; fi < 4; ++fi)
        #pragma unroll
        for (int fj = 0; fj < 4; ++fj)
          acc[fi][fj] = __builtin_amdgcn_mfma_f32_16x16x32_bf16(a[fi], b[fj], acc[fi][fj], 0, 0, 0);
    }
  }

  // epilogue: K = exp2(-(log2(e)/eps) * cost), bf16 store, fused row-sums
  const float SC = 14.426950408889634f;
  int colv[4]; float tqv[4];
  #pragma unroll
  for (int fj = 0; fj < 4; ++fj) {
    colv[fj] = col0 + wn * 64 + fj * 16 + lr;
    tqv[fj] = tsq[colv[fj]];
  }
  #pragma unroll
  for (int fi = 0; fi < 4; ++fi) {
    #pragma unroll
    for (int e = 0; e < 4; ++e) {
      int row = row0 + wm * 64 + fi * 16 + hi * 4 + e;
      float sq = ssq[row];
      float p = 0.f;
      #pragma unroll
      for (int fj = 0; fj < 4; ++fj) {
        float cost = sq + tqv[fj] - 2.0f * acc[fi][fj][e];
        float k = exp2f(-SC * cost);
        Kb[(size_t)row * MTGT + colv[fj]] = f2bf(k);
        p += k;
      }
      p += __shfl_xor(p, 1, 64);
      p += __shfl_xor(p, 2, 64);
      p += __shfl_xor(p, 4, 64);
      p += __shfl_xor(p, 8, 64);
      if (lr == 0) atomicAdd(&rowsum[row], p);
    }
  }
}

// ---------------- fence-free two-level tree barrier ----------------
__device__ __forceinline__ void grid_barrier(unsigned* garr, unsigned* root,
                                             unsigned* gen, unsigned& t) {
  __syncthreads();
  if (threadIdx.x == 0) {
    asm volatile("s_waitcnt vmcnt(0)" ::: "memory");
    unsigned g = (unsigned)(blockIdx.x >> 4);  // 16 groups of 16
    unsigned old = __hip_atomic_fetch_add(&garr[g * 64], 1u, __ATOMIC_RELAXED,
                                          __HIP_MEMORY_SCOPE_AGENT);
    if (old == t * GRPSZ + (GRPSZ - 1)) {
      unsigned r = __hip_atomic_fetch_add(root, 1u, __ATOMIC_RELAXED,
                                          __HIP_MEMORY_SCOPE_AGENT);
      if (r == t * NGRP + (NGRP - 1)) {
        __hip_atomic_store(gen, t + 1u, __ATOMIC_RELAXED, __HIP_MEMORY_SCOPE_AGENT);
      } else {
        while (gloadu(gen) < t + 1u) __builtin_amdgcn_s_sleep(1);
      }
    } else {
      while (gloadu(gen) < t + 1u) __builtin_amdgcn_s_sleep(1);
    }
    t += 1u;
  }
  __syncthreads();
}

// ---------------- kernel 3: Sinkhorn + fused final (REGULAR launch) ----------------
// 256 blocks x 1024 thr x 64KB LDS -> guaranteed co-resident on 256 CUs.
__global__ __launch_bounds__(NTHR) void ot_sinkhorn_kernel(
    const unsigned short* __restrict__ Kb, const float* __restrict__ rowsum,
    float* unew, float* v, unsigned* errb, float* ot, float* __restrict__ out,
    unsigned* garr, unsigned* root, unsigned* gen) {
  __shared__ float smem[16384];
  const int tid = threadIdx.x, bid = blockIdx.x;
  unsigned bt = 0;
  const float A_VAL = 1.0f / NSRC, B_VAL = 1.0f / MTGT;
  float uprev = 0.f;  // live in row-owner threads (tid % 256 == 0)

  // ---- phase 0: closed-form it0 phase A from GEMM row-sums ----
  if ((tid & 255) == 0) {
    int row = (bid << 2) + (tid >> 8);
    float un = A_VAL / (rowsum[row] + 1e-10f);
    uprev = un;
    gstoref(&unew[row], un);
    atomicMax(&errb[0], __float_as_uint(fabsf(un - 1.0f)));
  }
  grid_barrier(garr, root, gen, bt);

  for (int it = 0; it < MAXIT; ++it) {
    if (it > 0) {
      // ---- phase A: unew_i = a / (K v)_i ----
      #pragma unroll
      for (int q = 0; q < 16; ++q) {
        int j = tid + q * 1024;
        smem[j] = gloadf(&v[j]);
      }
      __syncthreads();
      const int r = tid >> 8, l2 = tid & 255;
      const int row = (bid << 2) + r;
      const u16x8* Kr = (const u16x8*)(Kb + (size_t)row * MTGT);
      float acc = 0.f;
      #pragma unroll
      for (int q = 0; q < 8; ++q) {
        int c8 = l2 + q * 256;
        u16x8 k8 = Kr[c8];
        float4 v0 = *(const float4*)(&smem[c8 * 8]);
        float4 v1 = *(const float4*)(&smem[c8 * 8 + 4]);
        acc += bf2f(k8[0]) * v0.x + bf2f(k8[1]) * v0.y +
               bf2f(k8[2]) * v0.z + bf2f(k8[3]) * v0.w +
               bf2f(k8[4]) * v1.x + bf2f(k8[5]) * v1.y +
               bf2f(k8[6]) * v1.z + bf2f(k8[7]) * v1.w;
      }
      __syncthreads();
      #pragma unroll
      for (int off = 32; off > 0; off >>= 1) acc += __shfl_down(acc, off, 64);
      if ((tid & 63) == 0) smem[tid >> 6] = acc;
      __syncthreads();
      if ((tid & 255) == 0) {
        float tot = smem[r * 4] + smem[r * 4 + 1] + smem[r * 4 + 2] + smem[r * 4 + 3];
        float un = A_VAL / (tot + 1e-10f);
        atomicMax(&errb[it], __float_as_uint(fabsf(un - uprev)));
        uprev = un;
        gstoref(&unew[row], un);
      }
      grid_barrier(garr, root, gen, bt);
    }
    // ---- phase B: v_j = b / (K^T unew)_j ; fused final on last iteration ----
    bool done = (__uint_as_float(gloadu(&errb[it])) < 0.001f);
    bool last = done || (it == MAXIT - 1);
    float* ulds = smem + 2048;
    float* tbuf = smem;
    float* wbuf = smem + 1024;
    ulds[tid] = gloadf(&unew[tid]);  // NTHR == NSRC
    __syncthreads();
    {
      const int cl = tid & 63, rg = tid >> 6;
      const int col = (bid << 6) + cl;
      float t = 0.f, w = 0.f;
      #pragma unroll 8
      for (int i = rg; i < NSRC; i += 16) {
        float ui = ulds[i];
        float k = bf2f(Kb[(size_t)i * MTGT + col]);
        t += k * ui;
        if (last) w += (k > 0.f) ? ui * k * (-0.1f * __logf(k)) : 0.f;
      }
      tbuf[tid] = t;
      if (last) wbuf[tid] = w;
    }
    __syncthreads();
    if (tid < 64) {
      float tt = 0.f, ww = 0.f;
      #pragma unroll
      for (int k16 = 0; k16 < 16; ++k16) {
        tt += tbuf[tid + k16 * 64];
        if (last) ww += wbuf[tid + k16 * 64];
      }
      float vj = B_VAL / (tt + 1e-10f);
      gstoref(&v[(bid << 6) + tid], vj);
      if (last) {
        float term = ww * vj;
        #pragma unroll
        for (int off = 32; off > 0; off >>= 1) term += __shfl_down(term, off, 64);
        if (tid == 0) atomicAdd(ot, term);
      }
    }
    grid_barrier(garr, root, gen, bt);
    if (done) break;
  }

  if (bid == 0 && tid == 0)
    out[0] = sqrtf(gloadf(ot) / (float)(NSRC + MTGT) + 1e-8f);
}

// ---------------- launcher ----------------
extern "C" void kernel_launch(void* const* d_in, const int* in_sizes, int n_in,
                              void* d_out, int out_size, void* d_ws, size_t ws_size,
                              hipStream_t stream) {
  const float* src = (const float*)d_in[0];  // 1024 x 768
  const float* tgt = (const float*)d_in[1];  // 16384 x 768
  float* out = (float*)d_out;
  char* ws = (char*)d_ws;

  unsigned short* Kb = (unsigned short*)ws;            // 32 MB
  char* ctrl = ws + 33554432;                          // 16 KB (zeroed by kernel 1)
  float* rowsum = (float*)(ctrl);                      //   4 KB
  unsigned* errb = (unsigned*)(ctrl + 4096);           //   512 B
  float* ot = (float*)(ctrl + 4608);                   //   4 B (pad 256)
  unsigned* garr = (unsigned*)(ctrl + 4864);           //   16 x 256 B
  unsigned* root = (unsigned*)(ctrl + 8960);           //   256 B
  unsigned* gen  = (unsigned*)(ctrl + 9216);           //   256 B
  unsigned short* srcb = (unsigned short*)(ws + 33570816);  // 1.5 MB
  unsigned short* tgtb = (unsigned short*)(ws + 35143680);  // 24 MB
  float* ssq  = (float*)(ws + 60309504);               // 4 KB
  float* tsq  = (float*)(ws + 60313600);               // 64 KB
  float* unew = (float*)(ws + 60379136);               // 4 KB
  float* v    = (float*)(ws + 60383232);               // 64 KB

  ot_convert_kernel<<<NSRC + MTGT, 192, 0, stream>>>(src, tgt, srcb, tgtb, ssq, tsq,
                                                     (unsigned*)ctrl);
  ot_gemmk_kernel<<<(NSRC / 128) * (MTGT / 128), 256, 0, stream>>>(srcb, tgtb, ssq, tsq,
                                                                   Kb, rowsum);
  ot_sinkhorn_kernel<<<NBLK, NTHR, 0, stream>>>(Kb, rowsum, unew, v, errb, ot, out,
                                                garr, root, gen);
}

// Round 6
// 189.903 us; speedup vs baseline: 5.5989x; 1.2336x over previous
//
#include <hip/hip_runtime.h>

#define NSRC 1024
#define MTGT 16384
#define DDIM 768
#define MAXIT 100
#define NBLK 256
#define NTHR 1024
#define NGRP 16
#define GRPSZ 16

typedef __attribute__((ext_vector_type(8))) short bf16x8;
typedef __attribute__((ext_vector_type(4))) float f32x4;
typedef __attribute__((ext_vector_type(4))) unsigned short u16x4;
typedef __attribute__((ext_vector_type(8))) unsigned short u16x8;

__device__ __forceinline__ unsigned short f2bf(float f) {
  unsigned u = __float_as_uint(f);
  u += 0x7FFFu + ((u >> 16) & 1u);
  return (unsigned short)(u >> 16);
}
__device__ __forceinline__ float bf2f(unsigned short h) {
  return __uint_as_float(((unsigned)h) << 16);
}
__device__ __forceinline__ void gstoref(float* p, float x) {
  __hip_atomic_store(p, x, __ATOMIC_RELAXED, __HIP_MEMORY_SCOPE_AGENT);
}
__device__ __forceinline__ float gloadf(const float* p) {
  return __hip_atomic_load(p, __ATOMIC_RELAXED, __HIP_MEMORY_SCOPE_AGENT);
}
__device__ __forceinline__ unsigned gloadu(const unsigned* p) {
  return __hip_atomic_load(p, __ATOMIC_RELAXED, __HIP_MEMORY_SCOPE_AGENT);
}
__device__ __forceinline__ void gl_lds16(const unsigned short* g, unsigned short* l) {
  __builtin_amdgcn_global_load_lds((__attribute__((address_space(1))) void*)g,
                                   (__attribute__((address_space(3))) void*)l, 16, 0, 0);
}

// ---------------- kernel 1: convert fp32->bf16 + row norms + zero ctrl/Kv ----------------
__global__ __launch_bounds__(192) void ot_convert_kernel(
    const float* __restrict__ src, const float* __restrict__ tgt,
    unsigned short* __restrict__ srcb, unsigned short* __restrict__ tgtb,
    float* __restrict__ ssq, float* __restrict__ tsq, unsigned* __restrict__ zreg) {
  __shared__ float sbuf[3];
  const int row = blockIdx.x;
  const float* inp;
  unsigned short* outp;
  if (row < NSRC) { inp = src + (size_t)row * DDIM; outp = srcb + (size_t)row * DDIM; }
  else { inp = tgt + (size_t)(row - NSRC) * DDIM; outp = tgtb + (size_t)(row - NSRC) * DDIM; }
  float4 v = *(const float4*)(inp + threadIdx.x * 4);
  u16x4 b; b[0] = f2bf(v.x); b[1] = f2bf(v.y); b[2] = f2bf(v.z); b[3] = f2bf(v.w);
  *(u16x4*)(outp + threadIdx.x * 4) = b;
  float acc = v.x * v.x + v.y * v.y + v.z * v.z + v.w * v.w;
  #pragma unroll
  for (int off = 32; off > 0; off >>= 1) acc += __shfl_down(acc, off, 64);
  int wave = threadIdx.x >> 6, lane = threadIdx.x & 63;
  if (lane == 0) sbuf[wave] = acc;
  __syncthreads();
  if (threadIdx.x == 0) {
    float t = sbuf[0] + sbuf[1] + sbuf[2];
    if (row < NSRC) ssq[row] = t; else tsq[row - NSRC] = t;
  }
  // zero ctrl+Kv region: 110592 words spread over blocks 0..575
  if (row < 576) zreg[row * 192 + threadIdx.x] = 0u;
}

// ---------------- kernel 2: Kb(bf16) = exp(-cost/eps), m97-style staging ----------------
__global__ __launch_bounds__(256) void ot_gemmk_kernel(
    const unsigned short* __restrict__ srcb, const unsigned short* __restrict__ tgtb,
    const float* __restrict__ ssq, const float* __restrict__ tsq,
    unsigned short* __restrict__ Kb, float* __restrict__ rowsum) {
  __shared__ __align__(16) unsigned short As[128 * 64];
  __shared__ __align__(16) unsigned short Bs[128 * 64];
  const int tile = (blockIdx.x & 7) * 128 + (blockIdx.x >> 3);
  const int tm = tile & 7, tn = tile >> 3;
  const int row0 = tm * 128, col0 = tn * 128;
  const int tid = threadIdx.x, lane = tid & 63, wave = tid >> 6;
  const int wm = wave >> 1, wn = wave & 1;
  const int lr = lane & 15, hi = lane >> 4;

  f32x4 acc[4][4];
  #pragma unroll
  for (int fi = 0; fi < 4; ++fi)
    #pragma unroll
    for (int fj = 0; fj < 4; ++fj) acc[fi][fj] = (f32x4){0.f, 0.f, 0.f, 0.f};

  for (int kt = 0; kt < DDIM / 64; ++kt) {
    __syncthreads();
    #pragma unroll
    for (int q = 0; q < 4; ++q) {
      int ch = tid + q * 256;
      int r = ch >> 3, c = ch & 7;
      int cg = c ^ (r & 7);
      gl_lds16(srcb + (size_t)(row0 + r) * DDIM + kt * 64 + cg * 8, As + ch * 8);
      gl_lds16(tgtb + (size_t)(col0 + r) * DDIM + kt * 64 + cg * 8, Bs + ch * 8);
    }
    __syncthreads();
    #pragma unroll
    for (int kc = 0; kc < 2; ++kc) {
      bf16x8 a[4], b[4];
      #pragma unroll
      for (int f = 0; f < 4; ++f) {
        int ra = wm * 64 + f * 16 + lr;
        a[f] = *(const bf16x8*)(As + ra * 64 + ((((kc << 2) | hi) ^ (ra & 7)) << 3));
        int rb = wn * 64 + f * 16 + lr;
        b[f] = *(const bf16x8*)(Bs + rb * 64 + ((((kc << 2) | hi) ^ (rb & 7)) << 3));
      }
      #pragma unroll
      for (int fi = 0; fi < 4; ++fi)
        #pragma unroll
        for (int fj = 0; fj < 4; ++fj)
          acc[fi][fj] = __builtin_amdgcn_mfma_f32_16x16x32_bf16(a[fi], b[fj], acc[fi][fj], 0, 0, 0);
    }
  }

  const float SC = 14.426950408889634f;  // log2(e)/0.1
  int colv[4]; float tqv[4];
  #pragma unroll
  for (int fj = 0; fj < 4; ++fj) {
    colv[fj] = col0 + wn * 64 + fj * 16 + lr;
    tqv[fj] = tsq[colv[fj]];
  }
  #pragma unroll
  for (int fi = 0; fi < 4; ++fi) {
    #pragma unroll
    for (int e = 0; e < 4; ++e) {
      int row = row0 + wm * 64 + fi * 16 + hi * 4 + e;
      float sq = ssq[row];
      float p = 0.f;
      #pragma unroll
      for (int fj = 0; fj < 4; ++fj) {
        float cost = sq + tqv[fj] - 2.0f * acc[fi][fj][e];
        float k = exp2f(-SC * cost);
        Kb[(size_t)row * MTGT + colv[fj]] = f2bf(k);
        p += k;
      }
      p += __shfl_xor(p, 1, 64);
      p += __shfl_xor(p, 2, 64);
      p += __shfl_xor(p, 4, 64);
      p += __shfl_xor(p, 8, 64);
      if (lr == 0) atomicAdd(&rowsum[row], p);
    }
  }
}

// ---------------- fence-free two-level tree barrier ----------------
__device__ __forceinline__ void grid_barrier(unsigned* garr, unsigned* root,
                                             unsigned* gen, unsigned& t) {
  __syncthreads();
  if (threadIdx.x == 0) {
    asm volatile("s_waitcnt vmcnt(0)" ::: "memory");
    unsigned g = (unsigned)(blockIdx.x >> 4);
    unsigned old = __hip_atomic_fetch_add(&garr[g * 64], 1u, __ATOMIC_RELAXED,
                                          __HIP_MEMORY_SCOPE_AGENT);
    if (old == t * GRPSZ + (GRPSZ - 1)) {
      unsigned r = __hip_atomic_fetch_add(root, 1u, __ATOMIC_RELAXED,
                                          __HIP_MEMORY_SCOPE_AGENT);
      if (r == t * NGRP + (NGRP - 1)) {
        __hip_atomic_store(gen, t + 1u, __ATOMIC_RELAXED, __HIP_MEMORY_SCOPE_AGENT);
      } else {
        while (gloadu(gen) < t + 1u) __builtin_amdgcn_s_sleep(1);
      }
    } else {
      while (gloadu(gen) < t + 1u) __builtin_amdgcn_s_sleep(1);
    }
    t += 1u;
  }
  __syncthreads();
}

// ---------------- kernel 3: column-resident Sinkhorn + fused final ----------------
// Each block owns 64 cols (128 KB K-slab, L2-resident). v is block-local (LDS).
// u maintained redundantly per block; only cross-block traffic: Kv partials + ot.
__global__ __launch_bounds__(NTHR) void ot_sinkhorn_kernel(
    const unsigned short* __restrict__ Kb, const float* __restrict__ rowsum,
    float* Kv, float* ot, float* __restrict__ out,
    unsigned* garr, unsigned* root, unsigned* gen) {
  __shared__ float ulds[NSRC];     // full u, redundant per block
  __shared__ float vlds[64];       // block-local v slab
  __shared__ float red[2048];      // cross-wave reduce: [0..1024) t, [1024..2048) w
  __shared__ int sflag[1];
  const int tid = threadIdx.x, bid = blockIdx.x;
  const int w = tid >> 6, l = tid & 63;
  const int r8 = l >> 3, c8 = l & 7;
  const size_t colbase = (size_t)bid * 64 + c8 * 8;
  unsigned bt = 0;
  const float A_VAL = 1.0f / NSRC, B_VAL = 1.0f / MTGT;
  float uold = 1.0f;  // thread tid owns u[tid]

  for (int it = 0; it < MAXIT; ++it) {
    // ---- u_new_i = a / ((K v)_i + 1e-10) ----
    float kv;
    if (it == 0) {
      kv = rowsum[tid];  // v == 1; rowsum from GEMM (kernel-boundary coherent)
    } else {
      // slab pass: p_i = sum_{j in my 64 cols} K_ij * v_j
      float4 va = *(const float4*)(&vlds[c8 * 8]);
      float4 vb = *(const float4*)(&vlds[c8 * 8 + 4]);
      float p[8];
      #pragma unroll
      for (int t = 0; t < 8; ++t) {
        int i = t * 128 + w * 8 + r8;
        u16x8 k8 = *(const u16x8*)(Kb + (size_t)i * MTGT + colbase);
        p[t] = bf2f(k8[0]) * va.x + bf2f(k8[1]) * va.y +
               bf2f(k8[2]) * va.z + bf2f(k8[3]) * va.w +
               bf2f(k8[4]) * vb.x + bf2f(k8[5]) * vb.y +
               bf2f(k8[6]) * vb.z + bf2f(k8[7]) * vb.w;
      }
      #pragma unroll
      for (int t = 0; t < 8; ++t) {
        p[t] += __shfl_xor(p[t], 1, 64);
        p[t] += __shfl_xor(p[t], 2, 64);
        p[t] += __shfl_xor(p[t], 4, 64);
      }
      float* kvs = Kv + (size_t)(it - 1) * NSRC;
      if (c8 == 0) {
        #pragma unroll
        for (int t = 0; t < 8; ++t) atomicAdd(&kvs[t * 128 + w * 8 + r8], p[t]);
      }
      grid_barrier(garr, root, gen, bt);
      kv = gloadf(&kvs[tid]);
    }
    float un = A_VAL / (kv + 1e-10f);
    // err = max_i |un - uold|  (redundant, bitwise-uniform across blocks)
    float d = fabsf(un - uold);
    #pragma unroll
    for (int off = 32; off > 0; off >>= 1) d = fmaxf(d, __shfl_xor(d, off, 64));
    if (l == 0) red[w] = d;
    ulds[tid] = un;
    uold = un;
    __syncthreads();
    if (tid == 0) {
      float dm = red[0];
      #pragma unroll
      for (int k = 1; k < 16; ++k) dm = fmaxf(dm, red[k]);
      sflag[0] = (dm < 0.001f) ? 1 : 0;
    }
    __syncthreads();
    const bool last = (sflag[0] != 0) || (it == MAXIT - 1);

    // ---- v_j = b / ((K^T u)_j + 1e-10), fused final on last ----
    float acc8[8], w8[8];
    #pragma unroll
    for (int e = 0; e < 8; ++e) { acc8[e] = 0.f; w8[e] = 0.f; }
    #pragma unroll
    for (int t = 0; t < 8; ++t) {
      int i = t * 128 + w * 8 + r8;
      float ui = ulds[i];
      u16x8 k8 = *(const u16x8*)(Kb + (size_t)i * MTGT + colbase);
      #pragma unroll
      for (int e = 0; e < 8; ++e) {
        float k = bf2f(k8[e]);
        acc8[e] += k * ui;
        if (last) w8[e] += (k > 0.f) ? ui * k * (-0.1f * __logf(k)) : 0.f;
      }
    }
    #pragma unroll
    for (int e = 0; e < 8; ++e) {
      acc8[e] += __shfl_xor(acc8[e], 8, 64);
      acc8[e] += __shfl_xor(acc8[e], 16, 64);
      acc8[e] += __shfl_xor(acc8[e], 32, 64);
      if (last) {
        w8[e] += __shfl_xor(w8[e], 8, 64);
        w8[e] += __shfl_xor(w8[e], 16, 64);
        w8[e] += __shfl_xor(w8[e], 32, 64);
      }
    }
    if (r8 == 0) {
      #pragma unroll
      for (int e = 0; e < 8; ++e) {
        red[w * 64 + c8 * 8 + e] = acc8[e];
        red[1024 + w * 64 + c8 * 8 + e] = w8[e];
      }
    }
    __syncthreads();
    if (tid < 64) {
      float t = 0.f, ww = 0.f;
      #pragma unroll
      for (int k16 = 0; k16 < 16; ++k16) {
        t += red[k16 * 64 + tid];
        if (last) ww += red[1024 + k16 * 64 + tid];
      }
      float vj = B_VAL / (t + 1e-10f);
      vlds[tid] = vj;
      if (last) {
        float term = ww * vj;
        #pragma unroll
        for (int off = 32; off > 0; off >>= 1) term += __shfl_down(term, off, 64);
        if (tid == 0) atomicAdd(ot, term);
      }
    }
    __syncthreads();
    if (last) break;
  }

  grid_barrier(garr, root, gen, bt);
  if (bid == 0 && tid == 0)
    out[0] = sqrtf(gloadf(ot) / (float)(NSRC + MTGT) + 1e-8f);
}

// ---------------- launcher ----------------
extern "C" void kernel_launch(void* const* d_in, const int* in_sizes, int n_in,
                              void* d_out, int out_size, void* d_ws, size_t ws_size,
                              hipStream_t stream) {
  const float* src = (const float*)d_in[0];  // 1024 x 768
  const float* tgt = (const float*)d_in[1];  // 16384 x 768
  float* out = (float*)d_out;
  char* ws = (char*)d_ws;

  unsigned short* Kb = (unsigned short*)ws;            // 32 MB
  char* ctrl = ws + 33554432;                          // 16 KB (zeroed)
  float* rowsum = (float*)(ctrl);                      //   4 KB
  float* ot = (float*)(ctrl + 4608);                   //   4 B
  unsigned* garr = (unsigned*)(ctrl + 4864);           //   16 x 256 B
  unsigned* root = (unsigned*)(ctrl + 8960);           //   256 B
  unsigned* gen  = (unsigned*)(ctrl + 9216);           //   256 B
  float* Kv = (float*)(ws + 33570816);                 // 416 KB (zeroed, 99 slots)
  unsigned short* srcb = (unsigned short*)(ws + 33996800);  // 1.5 MB
  unsigned short* tgtb = (unsigned short*)(ws + 35569664);  // 24 MB
  float* ssq  = (float*)(ws + 60735488);               // 4 KB
  float* tsq  = (float*)(ws + 60739584);               // 64 KB

  ot_convert_kernel<<<NSRC + MTGT, 192, 0, stream>>>(src, tgt, srcb, tgtb, ssq, tsq,
                                                     (unsigned*)ctrl);
  ot_gemmk_kernel<<<(NSRC / 128) * (MTGT / 128), 256, 0, stream>>>(srcb, tgtb, ssq, tsq,
                                                                   Kb, rowsum);
  ot_sinkhorn_kernel<<<NBLK, NTHR, 0, stream>>>(Kb, rowsum, Kv, ot, out, garr, root, gen);
}

// Round 7
// 179.056 us; speedup vs baseline: 5.9381x; 1.0606x over previous
//
#include <hip/hip_runtime.h>

#define NSRC 1024
#define MTGT 16384
#define DDIM 768
#define MAXIT 100
#define NBLK 256
#define NTHR 1024
#define NGRP 16
#define GRPSZ 16

typedef __attribute__((ext_vector_type(8))) short bf16x8;
typedef __attribute__((ext_vector_type(4))) float f32x4;
typedef __attribute__((ext_vector_type(4))) unsigned short u16x4;
typedef __attribute__((ext_vector_type(8))) unsigned short u16x8;

__device__ __forceinline__ unsigned short f2bf(float f) {
  unsigned u = __float_as_uint(f);
  u += 0x7FFFu + ((u >> 16) & 1u);
  return (unsigned short)(u >> 16);
}
__device__ __forceinline__ float bf2f(unsigned short h) {
  return __uint_as_float(((unsigned)h) << 16);
}
__device__ __forceinline__ float gloadf(const float* p) {
  return __hip_atomic_load(p, __ATOMIC_RELAXED, __HIP_MEMORY_SCOPE_AGENT);
}
__device__ __forceinline__ unsigned gloadu(const unsigned* p) {
  return __hip_atomic_load(p, __ATOMIC_RELAXED, __HIP_MEMORY_SCOPE_AGENT);
}

// ---------------- kernel 1: prep — A fp32->bf16, ssq, zero Kv/ctrl ----------------
__global__ __launch_bounds__(256) void ot_prep_kernel(
    const float* __restrict__ src, unsigned short* __restrict__ Ab,
    float* __restrict__ ssq, float* __restrict__ Kv, unsigned* __restrict__ ctrl) {
  const int gid = blockIdx.x * 256 + threadIdx.x;  // 65536 threads
  // convert A: 196608 float4 -> bf16x4
  #pragma unroll
  for (int k = 0; k < 3; ++k) {
    int idx = gid + k * 65536;
    float4 a = *(const float4*)(src + (size_t)idx * 4);
    u16x4 b; b[0] = f2bf(a.x); b[1] = f2bf(a.y); b[2] = f2bf(a.z); b[3] = f2bf(a.w);
    *(u16x4*)(Ab + (size_t)idx * 4) = b;
  }
  // row squared-norms: wave (64 threads) per row
  {
    int row = gid >> 6, l = gid & 63;
    float s = 0.f;
    #pragma unroll
    for (int k = 0; k < 3; ++k) {
      float4 a = *(const float4*)(src + (size_t)row * DDIM + (l + k * 64) * 4);
      s += a.x * a.x + a.y * a.y + a.z * a.z + a.w * a.w;
    }
    #pragma unroll
    for (int off = 32; off > 0; off >>= 1) s += __shfl_down(s, off, 64);
    if (l == 0) ssq[row] = s;
  }
  for (int i = gid; i < MAXIT * NSRC; i += 65536) Kv[i] = 0.f;
  if (gid < 4096) ctrl[gid] = 0u;
}

// ---------------- fence-free two-level tree barrier (monotonic) ----------------
__device__ __forceinline__ void grid_barrier(unsigned* garr, unsigned* root,
                                             unsigned* gen, unsigned& t) {
  __syncthreads();
  if (threadIdx.x == 0) {
    asm volatile("s_waitcnt vmcnt(0)" ::: "memory");
    unsigned g = (unsigned)(blockIdx.x >> 4);
    unsigned old = __hip_atomic_fetch_add(&garr[g * 64], 1u, __ATOMIC_RELAXED,
                                          __HIP_MEMORY_SCOPE_AGENT);
    if (old == t * GRPSZ + (GRPSZ - 1)) {
      unsigned r = __hip_atomic_fetch_add(root, 1u, __ATOMIC_RELAXED,
                                          __HIP_MEMORY_SCOPE_AGENT);
      if (r == t * NGRP + (NGRP - 1)) {
        __hip_atomic_store(gen, t + 1u, __ATOMIC_RELAXED, __HIP_MEMORY_SCOPE_AGENT);
      } else {
        while (gloadu(gen) < t + 1u) __builtin_amdgcn_s_sleep(1);
      }
    } else {
      while (gloadu(gen) < t + 1u) __builtin_amdgcn_s_sleep(1);
    }
    t += 1u;
  }
  __syncthreads();
}

// ---------------- kernel 2: fused GEMM(K in LDS) + Sinkhorn + final ----------------
// 256 blocks x 1024 thr, 1 block/CU (156 KB LDS). Block owns 64 K-cols.
// Wave w computes rows w*64..w*64+63 of the block's 1024x64 K-slab.
__global__ __launch_bounds__(NTHR) void ot_fused_kernel(
    const float* __restrict__ tgt, const unsigned short* __restrict__ Ab,
    const float* __restrict__ ssq,
    float* Kv, float* ot, float* __restrict__ out,
    unsigned* garr, unsigned* root, unsigned* gen) {
  __shared__ __align__(16) unsigned short Ks[NSRC * 64];  // 128 KB, XOR-swizzled
  __shared__ __align__(16) unsigned short Bs[2][4096];    // 16 KB dbuf, swizzled
  __shared__ float ulds[NSRC];                            // 4 KB
  __shared__ float red[1104];                             // 4.3 KB (16x68 padded)
  __shared__ float vlds[64];
  __shared__ float tsql[64];
  __shared__ int sflag;

  const int tid = threadIdx.x, bid = blockIdx.x;
  const int w = tid >> 6, l = tid & 63;
  const int lr = l & 15, hi = l >> 4;
  const int m0 = w * 64;
  const size_t c0 = (size_t)bid * 64;
  const int rB = tid >> 4, kq = tid & 15;   // B-stage: row(=K col) 0..63, k-quad 0..15
  unsigned bt = 0;
  const float A_VAL = 1.0f / NSRC, B_VAL = 1.0f / MTGT;

  // ================= GEMM phase: Ks = exp(-cost/eps) =================
  f32x4 acc[4][4];
  #pragma unroll
  for (int fi = 0; fi < 4; ++fi)
    #pragma unroll
    for (int fj = 0; fj < 4; ++fj) acc[fi][fj] = (f32x4){0.f, 0.f, 0.f, 0.f};

  float tsq_part = 0.f;
  // prologue: stage chunk 0
  {
    float4 bv = *(const float4*)(tgt + (c0 + rB) * DDIM + kq * 4);
    tsq_part += bv.x * bv.x + bv.y * bv.y + bv.z * bv.z + bv.w * bv.w;
    u16x4 bb; bb[0] = f2bf(bv.x); bb[1] = f2bf(bv.y); bb[2] = f2bf(bv.z); bb[3] = f2bf(bv.w);
    *(u16x4*)(&Bs[0][rB * 64 + (((kq >> 1) ^ (rB & 7)) << 3) + ((kq & 1) << 2)]) = bb;
  }
  __syncthreads();

  for (int kt = 0; kt < 12; ++kt) {
    // T14: issue next B-chunk load early
    float4 bv;
    if (kt < 11)
      bv = *(const float4*)(tgt + (c0 + rB) * DDIM + (kt + 1) * 64 + kq * 4);
    // MFMA on current buffer
    #pragma unroll
    for (int kc = 0; kc < 2; ++kc) {
      bf16x8 a[4];
      #pragma unroll
      for (int fi = 0; fi < 4; ++fi)
        a[fi] = *(const bf16x8*)(Ab + (size_t)(m0 + fi * 16 + lr) * DDIM +
                                 kt * 64 + kc * 32 + hi * 8);
      #pragma unroll
      for (int fj = 0; fj < 4; ++fj) {
        int rb = fj * 16 + lr;
        bf16x8 b = *(const bf16x8*)(&Bs[kt & 1][rb * 64 + ((((kc << 2) | hi) ^ (rb & 7)) << 3)]);
        #pragma unroll
        for (int fi = 0; fi < 4; ++fi)
          acc[fi][fj] = __builtin_amdgcn_mfma_f32_16x16x32_bf16(a[fi], b, acc[fi][fj], 0, 0, 0);
      }
    }
    // write-late: convert + ds_write next chunk
    if (kt < 11) {
      tsq_part += bv.x * bv.x + bv.y * bv.y + bv.z * bv.z + bv.w * bv.w;
      u16x4 bb; bb[0] = f2bf(bv.x); bb[1] = f2bf(bv.y); bb[2] = f2bf(bv.z); bb[3] = f2bf(bv.w);
      *(u16x4*)(&Bs[(kt + 1) & 1][rB * 64 + (((kq >> 1) ^ (rB & 7)) << 3) + ((kq & 1) << 2)]) = bb;
    }
    __syncthreads();
  }

  // tsq reduce: 16 threads (kq) share rB  (lane bits 0..3 == kq)
  {
    float s = tsq_part;
    s += __shfl_xor(s, 1, 64); s += __shfl_xor(s, 2, 64);
    s += __shfl_xor(s, 4, 64); s += __shfl_xor(s, 8, 64);
    if (kq == 0) tsql[rB] = s;
  }
  __syncthreads();

  // epilogue: K = exp2(-SC*cost) -> Ks (swizzled), bf16
  {
    const float SC = 14.426950408889634f;  // log2(e)/0.1
    #pragma unroll
    for (int fi = 0; fi < 4; ++fi) {
      #pragma unroll
      for (int e = 0; e < 4; ++e) {
        int r = m0 + fi * 16 + hi * 4 + e;
        float sq = ssq[r];
        #pragma unroll
        for (int fj = 0; fj < 4; ++fj) {
          int c = fj * 16 + lr;
          float cost = sq + tsql[c] - 2.0f * acc[fi][fj][e];
          float k = exp2f(-SC * cost);
          Ks[r * 64 + (((c >> 3) ^ (r & 7)) << 3) + (c & 7)] = f2bf(k);
        }
      }
    }
  }
  if (tid < 64) vlds[tid] = 1.0f;
  __syncthreads();

  // ================= Sinkhorn phase (K resident in LDS) =================
  float uold = 1.0f;  // thread owns row tid
  for (int it = 0; it < MAXIT; ++it) {
    // ---- Kv partial: p_i = sum_{j in my 64 cols} K[i][j] v[j]; i = tid ----
    {
      const int i = tid;
      float p = 0.f;
      #pragma unroll
      for (int lu = 0; lu < 8; ++lu) {
        int su = lu ^ (i & 7);
        u16x8 k8 = *(const u16x8*)(&Ks[i * 64 + su * 8]);
        float4 va = *(const float4*)(&vlds[lu * 8]);
        float4 vb = *(const float4*)(&vlds[lu * 8 + 4]);
        p += bf2f(k8[0]) * va.x + bf2f(k8[1]) * va.y +
             bf2f(k8[2]) * va.z + bf2f(k8[3]) * va.w +
             bf2f(k8[4]) * vb.x + bf2f(k8[5]) * vb.y +
             bf2f(k8[6]) * vb.z + bf2f(k8[7]) * vb.w;
      }
      atomicAdd(&Kv[it * NSRC + i], p);
    }
    grid_barrier(garr, root, gen, bt);
    // ---- u update + convergence (redundant, bitwise-uniform per block) ----
    float un, d;
    {
      float kv = gloadf(&Kv[it * NSRC + tid]);
      un = A_VAL / (kv + 1e-10f);
      d = fabsf(un - uold);
      #pragma unroll
      for (int off = 32; off > 0; off >>= 1) d = fmaxf(d, __shfl_xor(d, off, 64));
      if (l == 0) red[w] = d;
      ulds[tid] = un;
      uold = un;
    }
    __syncthreads();
    if (tid == 0) {
      float dm = red[0];
      #pragma unroll
      for (int k = 1; k < 16; ++k) dm = fmaxf(dm, red[k]);
      sflag = (dm < 0.001f) ? 1 : 0;
    }
    __syncthreads();
    const bool last = (sflag != 0) || (it == MAXIT - 1);

    // ---- KTu (block-local): t_c = sum_i K[i][c] u_i ; wave w rows w*64.. ----
    {
      float* wred = (float*)Bs;  // GEMM done; reuse 16 KB as scratch
      const int c = l;           // 0..63 (wave handles its 64-row stripe)
      float t = 0.f, ww = 0.f;
      #pragma unroll 8
      for (int r = 0; r < 64; ++r) {
        int i = w * 64 + r;
        float ui = ulds[i];
        float k = bf2f(Ks[i * 64 + (((c >> 3) ^ (i & 7)) << 3) + (c & 7)]);
        t += k * ui;
        if (last) ww += (k > 0.f) ? ui * k * (-0.1f * __logf(k)) : 0.f;
      }
      red[w * 68 + c] = t;
      if (last) wred[w * 68 + c] = ww;
      __syncthreads();
      if (tid < 64) {
        float tt = 0.f, wsum = 0.f;
        #pragma unroll
        for (int g = 0; g < 16; ++g) {
          tt += red[g * 68 + tid];
          if (last) wsum += wred[g * 68 + tid];
        }
        float vj = B_VAL / (tt + 1e-10f);
        vlds[tid] = vj;
        if (last) {
          float term = wsum * vj;
          #pragma unroll
          for (int off = 32; off > 0; off >>= 1) term += __shfl_down(term, off, 64);
          if (tid == 0) atomicAdd(ot, term);
        }
      }
    }
    __syncthreads();
    if (last) break;
  }

  grid_barrier(garr, root, gen, bt);
  if (bid == 0 && tid == 0)
    out[0] = sqrtf(gloadf(ot) / (float)(NSRC + MTGT) + 1e-8f);
}

// ---------------- launcher ----------------
extern "C" void kernel_launch(void* const* d_in, const int* in_sizes, int n_in,
                              void* d_out, int out_size, void* d_ws, size_t ws_size,
                              hipStream_t stream) {
  const float* src = (const float*)d_in[0];  // 1024 x 768
  const float* tgt = (const float*)d_in[1];  // 16384 x 768
  float* out = (float*)d_out;
  char* ws = (char*)d_ws;

  unsigned short* Ab = (unsigned short*)(ws);          // 1.5 MB bf16 A
  float* ssq = (float*)(ws + 1572864);                 // 4 KB
  float* Kv  = (float*)(ws + 1576960);                 // 400 KB (100 slots x 1024)
  unsigned* ctrl = (unsigned*)(ws + 1986560);          // 16 KB zeroed
  unsigned* garr = ctrl;                               // [16] stride-64 words
  unsigned* root = ctrl + 1024;
  unsigned* gen  = ctrl + 1040;
  float* ot      = (float*)(ctrl + 1056);

  ot_prep_kernel<<<256, 256, 0, stream>>>(src, Ab, ssq, Kv, ctrl);
  ot_fused_kernel<<<NBLK, NTHR, 0, stream>>>(tgt, Ab, ssq, Kv, ot, out,
                                             garr, root, gen);
}

// Round 8
// 178.547 us; speedup vs baseline: 5.9550x; 1.0028x over previous
//
#include <hip/hip_runtime.h>

#define NSRC 1024
#define MTGT 16384
#define DDIM 768
#define MAXIT 100
#define NBLK 256
#define NTHR 1024
#define NGRP 16
#define GRPSZ 16

typedef __attribute__((ext_vector_type(8))) short bf16x8;
typedef __attribute__((ext_vector_type(4))) float f32x4;
typedef __attribute__((ext_vector_type(4))) unsigned short u16x4;
typedef __attribute__((ext_vector_type(8))) unsigned short u16x8;

__device__ __forceinline__ unsigned short f2bf(float f) {
  unsigned u = __float_as_uint(f);
  u += 0x7FFFu + ((u >> 16) & 1u);
  return (unsigned short)(u >> 16);
}
__device__ __forceinline__ float bf2f(unsigned short h) {
  return __uint_as_float(((unsigned)h) << 16);
}
__device__ __forceinline__ void gstoref(float* p, float x) {
  __hip_atomic_store(p, x, __ATOMIC_RELAXED, __HIP_MEMORY_SCOPE_AGENT);
}
__device__ __forceinline__ float gloadf(const float* p) {
  return __hip_atomic_load(p, __ATOMIC_RELAXED, __HIP_MEMORY_SCOPE_AGENT);
}
__device__ __forceinline__ unsigned gloadu(const unsigned* p) {
  return __hip_atomic_load(p, __ATOMIC_RELAXED, __HIP_MEMORY_SCOPE_AGENT);
}

// ---------------- kernel 1: prep — A fp32->bf16, ssq, zero ctrl ----------------
__global__ __launch_bounds__(256) void ot_prep_kernel(
    const float* __restrict__ src, unsigned short* __restrict__ Ab,
    float* __restrict__ ssq, unsigned* __restrict__ ctrl) {
  const int gid = blockIdx.x * 256 + threadIdx.x;  // 65536 threads
  #pragma unroll
  for (int k = 0; k < 3; ++k) {
    int idx = gid + k * 65536;
    float4 a = *(const float4*)(src + (size_t)idx * 4);
    u16x4 b; b[0] = f2bf(a.x); b[1] = f2bf(a.y); b[2] = f2bf(a.z); b[3] = f2bf(a.w);
    *(u16x4*)(Ab + (size_t)idx * 4) = b;
  }
  {
    int row = gid >> 6, l = gid & 63;
    float s = 0.f;
    #pragma unroll
    for (int k = 0; k < 3; ++k) {
      float4 a = *(const float4*)(src + (size_t)row * DDIM + (l + k * 64) * 4);
      s += a.x * a.x + a.y * a.y + a.z * a.z + a.w * a.w;
    }
    #pragma unroll
    for (int off = 32; off > 0; off >>= 1) s += __shfl_down(s, off, 64);
    if (l == 0) ssq[row] = s;
  }
  if (gid < 4096) ctrl[gid] = 0u;
}

// ---------------- fence-free two-level tree barrier (monotonic) ----------------
__device__ __forceinline__ void grid_barrier(unsigned* garr, unsigned* root,
                                             unsigned* gen, unsigned& t) {
  __syncthreads();
  if (threadIdx.x == 0) {
    asm volatile("s_waitcnt vmcnt(0)" ::: "memory");
    unsigned g = (unsigned)(blockIdx.x >> 4);
    unsigned old = __hip_atomic_fetch_add(&garr[g * 64], 1u, __ATOMIC_RELAXED,
                                          __HIP_MEMORY_SCOPE_AGENT);
    if (old == t * GRPSZ + (GRPSZ - 1)) {
      unsigned r = __hip_atomic_fetch_add(root, 1u, __ATOMIC_RELAXED,
                                          __HIP_MEMORY_SCOPE_AGENT);
      if (r == t * NGRP + (NGRP - 1)) {
        __hip_atomic_store(gen, t + 1u, __ATOMIC_RELAXED, __HIP_MEMORY_SCOPE_AGENT);
      } else {
        while (gloadu(gen) < t + 1u) __builtin_amdgcn_s_sleep(1);
      }
    } else {
      while (gloadu(gen) < t + 1u) __builtin_amdgcn_s_sleep(1);
    }
    t += 1u;
  }
  __syncthreads();
}

// ---------------- kernel 2: fused GEMM(K in LDS) + Sinkhorn + final ----------------
// 256 blocks x 1024 thr, 1 block/CU. Block owns 64 K-cols in LDS.
// Cross-block exchange: non-atomic staged Kv reduction + otp partials.
__global__ __launch_bounds__(NTHR) void ot_fused_kernel(
    const float* __restrict__ tgt, const unsigned short* __restrict__ Ab,
    const float* __restrict__ ssq,
    float* Kvp, float* Kvf, float* otp, float* __restrict__ out,
    unsigned* garr, unsigned* root, unsigned* gen) {
  __shared__ __align__(16) unsigned short Ks[NSRC * 64];  // 128 KB, XOR-swizzled
  __shared__ __align__(16) unsigned short Bs[2][4096];    // 16 KB dbuf, swizzled
  __shared__ float ulds[NSRC];                            // 4 KB
  __shared__ float red[1104];
  __shared__ float vlds[64];
  __shared__ float tsql[64];
  __shared__ int sflag;

  const int tid = threadIdx.x, bid = blockIdx.x;
  const int w = tid >> 6, l = tid & 63;
  const int lr = l & 15, hi = l >> 4;
  const int m0 = w * 64;
  const size_t c0 = (size_t)bid * 64;
  const int rB = tid >> 4, kq = tid & 15;
  unsigned bt = 0;
  const float A_VAL = 1.0f / NSRC, B_VAL = 1.0f / MTGT;

  // ================= GEMM phase: Ks = exp(-cost/eps) =================
  f32x4 acc[4][4];
  #pragma unroll
  for (int fi = 0; fi < 4; ++fi)
    #pragma unroll
    for (int fj = 0; fj < 4; ++fj) acc[fi][fj] = (f32x4){0.f, 0.f, 0.f, 0.f};

  float tsq_part = 0.f;
  {
    float4 bv = *(const float4*)(tgt + (c0 + rB) * DDIM + kq * 4);
    tsq_part += bv.x * bv.x + bv.y * bv.y + bv.z * bv.z + bv.w * bv.w;
    u16x4 bb; bb[0] = f2bf(bv.x); bb[1] = f2bf(bv.y); bb[2] = f2bf(bv.z); bb[3] = f2bf(bv.w);
    *(u16x4*)(&Bs[0][rB * 64 + (((kq >> 1) ^ (rB & 7)) << 3) + ((kq & 1) << 2)]) = bb;
  }
  __syncthreads();

  for (int kt = 0; kt < 12; ++kt) {
    float4 bv;
    if (kt < 11)
      bv = *(const float4*)(tgt + (c0 + rB) * DDIM + (kt + 1) * 64 + kq * 4);
    #pragma unroll
    for (int kc = 0; kc < 2; ++kc) {
      bf16x8 a[4];
      #pragma unroll
      for (int fi = 0; fi < 4; ++fi)
        a[fi] = *(const bf16x8*)(Ab + (size_t)(m0 + fi * 16 + lr) * DDIM +
                                 kt * 64 + kc * 32 + hi * 8);
      #pragma unroll
      for (int fj = 0; fj < 4; ++fj) {
        int rb = fj * 16 + lr;
        bf16x8 b = *(const bf16x8*)(&Bs[kt & 1][rb * 64 + ((((kc << 2) | hi) ^ (rb & 7)) << 3)]);
        #pragma unroll
        for (int fi = 0; fi < 4; ++fi)
          acc[fi][fj] = __builtin_amdgcn_mfma_f32_16x16x32_bf16(a[fi], b, acc[fi][fj], 0, 0, 0);
      }
    }
    if (kt < 11) {
      tsq_part += bv.x * bv.x + bv.y * bv.y + bv.z * bv.z + bv.w * bv.w;
      u16x4 bb; bb[0] = f2bf(bv.x); bb[1] = f2bf(bv.y); bb[2] = f2bf(bv.z); bb[3] = f2bf(bv.w);
      *(u16x4*)(&Bs[(kt + 1) & 1][rB * 64 + (((kq >> 1) ^ (rB & 7)) << 3) + ((kq & 1) << 2)]) = bb;
    }
    __syncthreads();
  }

  {
    float s = tsq_part;
    s += __shfl_xor(s, 1, 64); s += __shfl_xor(s, 2, 64);
    s += __shfl_xor(s, 4, 64); s += __shfl_xor(s, 8, 64);
    if (kq == 0) tsql[rB] = s;
  }
  __syncthreads();

  {
    const float SC = 14.426950408889634f;  // log2(e)/0.1
    #pragma unroll
    for (int fi = 0; fi < 4; ++fi) {
      #pragma unroll
      for (int e = 0; e < 4; ++e) {
        int r = m0 + fi * 16 + hi * 4 + e;
        float sq = ssq[r];
        #pragma unroll
        for (int fj = 0; fj < 4; ++fj) {
          int c = fj * 16 + lr;
          float cost = sq + tsql[c] - 2.0f * acc[fi][fj][e];
          float k = exp2f(-SC * cost);
          Ks[r * 64 + (((c >> 3) ^ (r & 7)) << 3) + (c & 7)] = f2bf(k);
        }
      }
    }
  }
  if (tid < 64) vlds[tid] = 1.0f;
  __syncthreads();

  // ================= Sinkhorn phase (K resident in LDS) =================
  float uold = 1.0f;  // thread owns row tid
  for (int it = 0; it < MAXIT; ++it) {
    // ---- stage 1: block-local Kv partial for row i=tid over my 64 cols ----
    {
      const int i = tid;
      float p = 0.f;
      #pragma unroll
      for (int lu = 0; lu < 8; ++lu) {
        int su = lu ^ (i & 7);
        u16x8 k8 = *(const u16x8*)(&Ks[i * 64 + su * 8]);
        float4 va = *(const float4*)(&vlds[lu * 8]);
        float4 vb = *(const float4*)(&vlds[lu * 8 + 4]);
        p += bf2f(k8[0]) * va.x + bf2f(k8[1]) * va.y +
             bf2f(k8[2]) * va.z + bf2f(k8[3]) * va.w +
             bf2f(k8[4]) * vb.x + bf2f(k8[5]) * vb.y +
             bf2f(k8[6]) * vb.z + bf2f(k8[7]) * vb.w;
      }
      gstoref(&Kvp[(size_t)bid * NSRC + tid], p);  // coalesced, non-atomic
    }
    grid_barrier(garr, root, gen, bt);
    // ---- stage 2: block b reduces 256 partials for its 4 rows 4b+r ----
    {
      float s = gloadf(&Kvp[(size_t)(tid >> 2) * NSRC + (bid << 2) + (tid & 3)]);
      s += __shfl_xor(s, 4, 64);  s += __shfl_xor(s, 8, 64);
      s += __shfl_xor(s, 16, 64); s += __shfl_xor(s, 32, 64);
      if (l < 4) red[w * 4 + l] = s;
      __syncthreads();
      if (tid < 4) {
        float t = 0.f;
        #pragma unroll
        for (int g = 0; g < 16; ++g) t += red[g * 4 + tid];
        gstoref(&Kvf[(bid << 2) + tid], t);
      }
    }
    grid_barrier(garr, root, gen, bt);
    // ---- u update + convergence (redundant, uniform across blocks) ----
    {
      float kv = gloadf(&Kvf[tid]);
      float un = A_VAL / (kv + 1e-10f);
      float d = fabsf(un - uold);
      #pragma unroll
      for (int off = 32; off > 0; off >>= 1) d = fmaxf(d, __shfl_xor(d, off, 64));
      if (l == 0) red[w] = d;
      ulds[tid] = un;
      uold = un;
    }
    __syncthreads();
    if (tid == 0) {
      float dm = red[0];
      #pragma unroll
      for (int k = 1; k < 16; ++k) dm = fmaxf(dm, red[k]);
      sflag = (dm < 0.001f) ? 1 : 0;
    }
    __syncthreads();
    const bool last = (sflag != 0) || (it == MAXIT - 1);

    // ---- KTu (block-local): t_c = sum_i K[i][c] u_i ----
    {
      float* wred = (float*)Bs;  // reuse 16 KB as scratch
      const int c = l;
      float t = 0.f, ww = 0.f;
      #pragma unroll 8
      for (int r = 0; r < 64; ++r) {
        int i = w * 64 + r;
        float ui = ulds[i];
        float k = bf2f(Ks[i * 64 + (((c >> 3) ^ (i & 7)) << 3) + (c & 7)]);
        t += k * ui;
        if (last) ww += (k > 0.f) ? ui * k * (-0.1f * __logf(k)) : 0.f;
      }
      red[w * 68 + c] = t;
      if (last) wred[w * 68 + c] = ww;
      __syncthreads();
      if (tid < 64) {
        float tt = 0.f, wsum = 0.f;
        #pragma unroll
        for (int g = 0; g < 16; ++g) {
          tt += red[g * 68 + tid];
          if (last) wsum += wred[g * 68 + tid];
        }
        float vj = B_VAL / (tt + 1e-10f);
        vlds[tid] = vj;
        if (last) {
          float term = wsum * vj;
          #pragma unroll
          for (int off = 32; off > 0; off >>= 1) term += __shfl_down(term, off, 64);
          if (tid == 0) gstoref(&otp[bid], term);  // per-block partial, no atomic
        }
      }
    }
    __syncthreads();
    if (last) break;
  }

  grid_barrier(garr, root, gen, bt);
  // block 0 reduces the 256 ot partials
  if (bid == 0) {
    float s = (tid < NBLK) ? gloadf(&otp[tid]) : 0.f;
    if (tid < NBLK) {
      #pragma unroll
      for (int off = 32; off > 0; off >>= 1) s += __shfl_down(s, off, 64);
      if (l == 0) red[w] = s;
    }
    __syncthreads();
    if (tid == 0) {
      float tot = red[0] + red[1] + red[2] + red[3];
      out[0] = sqrtf(tot / (float)(NSRC + MTGT) + 1e-8f);
    }
  }
}

// ---------------- launcher ----------------
extern "C" void kernel_launch(void* const* d_in, const int* in_sizes, int n_in,
                              void* d_out, int out_size, void* d_ws, size_t ws_size,
                              hipStream_t stream) {
  const float* src = (const float*)d_in[0];  // 1024 x 768
  const float* tgt = (const float*)d_in[1];  // 16384 x 768
  float* out = (float*)d_out;
  char* ws = (char*)d_ws;

  unsigned short* Ab = (unsigned short*)(ws);          // 1.5 MB bf16 A
  float* ssq = (float*)(ws + 1572864);                 // 4 KB
  float* Kvp = (float*)(ws + 1576960);                 // 1 MB  [256][1024] partials
  float* Kvf = (float*)(ws + 2625536);                 // 4 KB  final Kv
  float* otp = (float*)(ws + 2629632);                 // 1 KB  ot partials
  unsigned* ctrl = (unsigned*)(ws + 2630656);          // 16 KB zeroed
  unsigned* garr = ctrl;                               // [16] stride-64 words
  unsigned* root = ctrl + 1024;
  unsigned* gen  = ctrl + 1040;

  ot_prep_kernel<<<256, 256, 0, stream>>>(src, Ab, ssq, ctrl);
  ot_fused_kernel<<<NBLK, NTHR, 0, stream>>>(tgt, Ab, ssq, Kvp, Kvf, otp, out,
                                             garr, root, gen);
}